// Round 2
// baseline (21229.509 us; speedup 1.0000x reference)
//
#include <hip/hip_runtime.h>
#include <hip/hip_bf16.h>

// ---------------------------------------------------------------------------
// VQ-VAE forward. fp32 math, bf16 storage for large intermediates.
// x[32,3,256,256] -> h1 bf16[32,32,128,128] -> h2 f32[32,64,64,64]
// -> z f32[32,64,64,64] -> VQ -> q bf16 -> d1 bf16[32,64,128,128]
// -> fused(convT2+relu+conv3+sigmoid) -> out f32[32,3,256,256] ++ loss
// Peak workspace: 112 MiB + 2 KiB.
// ---------------------------------------------------------------------------

__device__ __forceinline__ float ldf(const float* p) { return *p; }
__device__ __forceinline__ float ldf(const __hip_bfloat16* p) { return __bfloat162float(*p); }
__device__ __forceinline__ void stf(float* p, float v) { *p = v; }
__device__ __forceinline__ void stf(__hip_bfloat16* p, float v) { *p = __float2bfloat16(v); }

// Generic direct conv. ACT: 0=none, 1=relu.
template <typename Tin, typename Tout, int IC, int K, int S, int P, int ACT>
__global__ __launch_bounds__(256) void conv_k(
    const Tin* __restrict__ in, const float* __restrict__ w,
    const float* __restrict__ bias, Tout* __restrict__ out,
    int B, int OC, int IH, int IW, int OH, int OW) {
  int idx = blockIdx.x * 256 + threadIdx.x;
  int total = B * OC * OH * OW;
  if (idx >= total) return;
  int ox = idx % OW;
  int t = idx / OW;
  int oy = t % OH; t /= OH;
  int oc = t % OC;
  int b = t / OC;
  float acc = bias[oc];
  const float* wbase = w + oc * IC * K * K;
  const Tin* ibase = in + (size_t)(b * IC) * IH * IW;
#pragma unroll
  for (int kh = 0; kh < K; ++kh) {
    int iy = oy * S - P + kh;
    if ((unsigned)iy >= (unsigned)IH) continue;
#pragma unroll
    for (int kw = 0; kw < K; ++kw) {
      int ix = ox * S - P + kw;
      if ((unsigned)ix >= (unsigned)IW) continue;
      const Tin* ip = ibase + iy * IW + ix;
      const float* wp = wbase + kh * K + kw;
#pragma unroll
      for (int ic = 0; ic < IC; ++ic)
        acc += ldf(ip + ic * IH * IW) * wp[ic * K * K];
    }
  }
  if (ACT == 1) acc = fmaxf(acc, 0.f);
  stf(out + idx, acc);
}

// Direct ConvTranspose2d, k=4 s=2 p=1, torch weight layout w[IC][OC][4][4], ReLU.
template <typename Tin, typename Tout, int IC>
__global__ __launch_bounds__(256) void convt_k(
    const Tin* __restrict__ in, const float* __restrict__ w,
    const float* __restrict__ bias, Tout* __restrict__ out,
    int B, int OC, int IH, int IW, int OH, int OW) {
  int idx = blockIdx.x * 256 + threadIdx.x;
  int total = B * OC * OH * OW;
  if (idx >= total) return;
  int ox = idx % OW;
  int t = idx / OW;
  int oy = t % OH; t /= OH;
  int oc = t % OC;
  int b = t / OC;
  float acc = bias[oc];
  int ty = oy + 1;  // = iy*2 + ky
  int tx = ox + 1;
  for (int ky = (ty & 1); ky < 4; ky += 2) {
    int iy = (ty - ky) >> 1;
    if ((unsigned)iy >= (unsigned)IH) continue;
    for (int kx = (tx & 1); kx < 4; kx += 2) {
      int ix = (tx - kx) >> 1;
      if ((unsigned)ix >= (unsigned)IW) continue;
      const Tin* ip = in + ((size_t)(b * IC) * IH + iy) * IW + ix;
      const float* wp = w + oc * 16 + ky * 4 + kx;
#pragma unroll
      for (int i = 0; i < IC; ++i)
        acc += ldf(ip + (size_t)i * IH * IW) * wp[i * OC * 16];
    }
  }
  acc = fmaxf(acc, 0.f);
  stf(out + idx, acc);
}

// Precompute ||c_k||^2; zero the loss slot.
__global__ void cnorm_zero_k(const float* __restrict__ cb, float* __restrict__ cnorm,
                             float* __restrict__ loss) {
  int k = blockIdx.x * blockDim.x + threadIdx.x;
  if (k < 512) {
    float s = 0.f;
#pragma unroll
    for (int d = 0; d < 64; ++d) {
      float c = cb[k * 64 + d];
      s += c * c;
    }
    cnorm[k] = s;
  }
  if (k == 0) *loss = 0.f;
}

// VQ: argmin over 512 codes per z-vector, write q (bf16), accumulate loss.
__global__ __launch_bounds__(256) void vq_k(
    const float* __restrict__ z, const float* __restrict__ cb,
    const float* __restrict__ cnorm, __hip_bfloat16* __restrict__ q,
    float* __restrict__ loss) {
  __shared__ float cbs[256 * 64];  // 64 KB: half the codebook at a time
  int tid = threadIdx.x;
  int n = blockIdx.x * 256 + tid;  // [0, 131072)
  int b = n >> 12;
  int hw = n & 4095;
  const float* zp = z + (b << 18) + hw;  // z[b][d][hw], d-stride 4096
  float zr[64];
#pragma unroll
  for (int d = 0; d < 64; ++d) zr[d] = zp[d << 12];

  float best = 3.4e38f;
  int bestk = 0;
  for (int half = 0; half < 2; ++half) {
    __syncthreads();
    const float4* src = (const float4*)(cb + half * 256 * 64);
    float4* dst = (float4*)cbs;
    for (int i = tid; i < 4096; i += 256) dst[i] = src[i];
    __syncthreads();
    for (int k = 0; k < 256; ++k) {
      const float4* row = (const float4*)(cbs + k * 64);
      float a0 = 0.f, a1 = 0.f, a2 = 0.f, a3 = 0.f;
#pragma unroll
      for (int j = 0; j < 16; j += 4) {
        float4 c0 = row[j], c1 = row[j + 1], c2 = row[j + 2], c3 = row[j + 3];
        a0 += c0.x * zr[4 * j + 0] + c0.y * zr[4 * j + 1] + c0.z * zr[4 * j + 2] + c0.w * zr[4 * j + 3];
        a1 += c1.x * zr[4 * j + 4] + c1.y * zr[4 * j + 5] + c1.z * zr[4 * j + 6] + c1.w * zr[4 * j + 7];
        a2 += c2.x * zr[4 * j + 8] + c2.y * zr[4 * j + 9] + c2.z * zr[4 * j + 10] + c2.w * zr[4 * j + 11];
        a3 += c3.x * zr[4 * j + 12] + c3.y * zr[4 * j + 13] + c3.z * zr[4 * j + 14] + c3.w * zr[4 * j + 15];
      }
      float dot = (a0 + a1) + (a2 + a3);
      float dist = cnorm[half * 256 + k] - 2.f * dot;
      if (dist < best) { best = dist; bestk = half * 256 + k; }
    }
  }

  const float* crow = cb + bestk * 64;
  __hip_bfloat16* qp = q + (b << 18) + hw;
  float lsum = 0.f;
#pragma unroll
  for (int d = 0; d < 64; ++d) {
    float c = crow[d];
    float diff = c - zr[d];
    lsum += diff * diff;
    qp[d << 12] = __float2bfloat16(c);
  }

  __syncthreads();  // reuse cbs for reduction
  cbs[tid] = lsum;
  __syncthreads();
  for (int s = 128; s > 0; s >>= 1) {
    if (tid < s) cbs[tid] += cbs[tid + s];
    __syncthreads();
  }
  if (tid == 0) atomicAdd(loss, cbs[0] * (1.25f / 8388608.f));
}

// Fused tail: d2 = relu(convT(d1, w2, b2)) computed tile-wise into LDS, then
// out = sigmoid(conv3x3(d2, w3, b3)). d1 bf16 [32,64,128,128]; out f32.
__global__ __launch_bounds__(256) void fused_tail_k(
    const __hip_bfloat16* __restrict__ d1, const float* __restrict__ w2,
    const float* __restrict__ b2, const float* __restrict__ w3,
    const float* __restrict__ b3, float* __restrict__ out) {
  __shared__ float tile[32][18][18];  // 41.5 KB
  int blk = blockIdx.x;
  int tx = blk & 15;
  int t = blk >> 4;
  int ty = t & 15;
  int b = t >> 4;
  int tid = threadIdx.x;

  // Phase 1: d2 halo tile (32 ch, 18x18) at origin (ty*16-1, tx*16-1).
  for (int i = tid; i < 32 * 18 * 18; i += 256) {
    int xx = i % 18;
    int r = i / 18;
    int yy = r % 18;
    int c2 = r / 18;
    int oy = ty * 16 - 1 + yy;
    int ox = tx * 16 - 1 + xx;
    float acc = 0.f;
    if ((unsigned)oy < 256u && (unsigned)ox < 256u) {
      acc = b2[c2];
      int tyy = oy + 1, txx = ox + 1;
      for (int ky = (tyy & 1); ky < 4; ky += 2) {
        int iy = (tyy - ky) >> 1;
        if ((unsigned)iy >= 128u) continue;
        for (int kx = (txx & 1); kx < 4; kx += 2) {
          int ix = (txx - kx) >> 1;
          if ((unsigned)ix >= 128u) continue;
          const __hip_bfloat16* ip = d1 + ((size_t)(b * 64) * 128 + iy) * 128 + ix;
          const float* wp = w2 + c2 * 16 + ky * 4 + kx;
#pragma unroll
          for (int ic = 0; ic < 64; ++ic)
            acc += __bfloat162float(ip[ic * 128 * 128]) * wp[ic * 32 * 16];
        }
      }
      acc = fmaxf(acc, 0.f);
    }
    tile[c2][yy][xx] = acc;
  }
  __syncthreads();

  // Phase 2: 3x3 conv + sigmoid on the 16x16 tile, 3 output channels.
  for (int i = tid; i < 3 * 16 * 16; i += 256) {
    int xx = i & 15;
    int r = i >> 4;
    int yy = r & 15;
    int oc = r >> 4;
    float acc = b3[oc];
#pragma unroll
    for (int kh = 0; kh < 3; ++kh)
#pragma unroll
      for (int kw = 0; kw < 3; ++kw) {
        const float* wp = w3 + oc * 32 * 9 + kh * 3 + kw;
#pragma unroll
        for (int ic = 0; ic < 32; ++ic)
          acc += tile[ic][yy + kh][xx + kw] * wp[ic * 9];
      }
    int oy = ty * 16 + yy, ox = tx * 16 + xx;
    out[((size_t)(b * 3 + oc) * 256 + oy) * 256 + ox] = 1.f / (1.f + expf(-acc));
  }
}

extern "C" void kernel_launch(void* const* d_in, const int* in_sizes, int n_in,
                              void* d_out, int out_size, void* d_ws, size_t ws_size,
                              hipStream_t stream) {
  const float* x   = (const float*)d_in[0];
  const float* ew1 = (const float*)d_in[1];
  const float* eb1 = (const float*)d_in[2];
  const float* ew2 = (const float*)d_in[3];
  const float* eb2 = (const float*)d_in[4];
  const float* ew3 = (const float*)d_in[5];
  const float* eb3 = (const float*)d_in[6];
  const float* cb  = (const float*)d_in[7];
  const float* dw1 = (const float*)d_in[8];
  const float* db1 = (const float*)d_in[9];
  const float* dw2 = (const float*)d_in[10];
  const float* db2 = (const float*)d_in[11];
  const float* dw3 = (const float*)d_in[12];
  const float* db3 = (const float*)d_in[13];
  float* out = (float*)d_out;

  // Workspace layout (MiB offsets), peak 112 MiB + 2 KiB:
  //   h1 bf16 [0,32) ; h2 f32 [32,64) ; z f32 [0,32) ; q bf16 [32,48) ;
  //   d1 bf16 [48,112) ; cnorm [112,112+2KiB)
  char* ws = (char*)d_ws;
  __hip_bfloat16* h1 = (__hip_bfloat16*)ws;
  float*          h2 = (float*)(ws + (size_t)(32u << 20));
  float*          z  = (float*)ws;
  __hip_bfloat16* q  = (__hip_bfloat16*)(ws + (size_t)(32u << 20));
  __hip_bfloat16* d1 = (__hip_bfloat16*)(ws + (size_t)(48u << 20));
  float*       cnorm = (float*)(ws + (size_t)(112u << 20));
  float*       loss  = out + 6291456;

  const int B = 32;

  cnorm_zero_k<<<2, 256, 0, stream>>>(cb, cnorm, loss);

  {  // enc conv1: 3->32, k4 s2 p1, relu. 256x256 -> 128x128
    int total = 32 * 32 * 128 * 128;
    conv_k<float, __hip_bfloat16, 3, 4, 2, 1, 1><<<(total + 255) / 256, 256, 0, stream>>>(
        x, ew1, eb1, h1, B, 32, 256, 256, 128, 128);
  }
  {  // enc conv2: 32->64, k4 s2 p1, relu. 128x128 -> 64x64
    int total = 32 * 64 * 64 * 64;
    conv_k<__hip_bfloat16, float, 32, 4, 2, 1, 1><<<(total + 255) / 256, 256, 0, stream>>>(
        h1, ew2, eb2, h2, B, 64, 128, 128, 64, 64);
  }
  {  // enc conv3: 64->64, k3 s1 p1. 64x64 -> 64x64
    int total = 32 * 64 * 64 * 64;
    conv_k<float, float, 64, 3, 1, 1, 0><<<(total + 255) / 256, 256, 0, stream>>>(
        h2, ew3, eb3, z, B, 64, 64, 64, 64, 64);
  }
  // VQ: 131072 vectors
  vq_k<<<512, 256, 0, stream>>>(z, cb, cnorm, q, loss);
  {  // dec convT1: 64->64, k4 s2 p1, relu. 64x64 -> 128x128
    int total = 32 * 64 * 128 * 128;
    convt_k<__hip_bfloat16, __hip_bfloat16, 64><<<(total + 255) / 256, 256, 0, stream>>>(
        q, dw1, db1, d1, B, 64, 64, 64, 128, 128);
  }
  // Fused: convT2 (64->32, k4 s2 p1, relu) + conv3 (32->3, k3 s1 p1) + sigmoid
  fused_tail_k<<<32 * 16 * 16, 256, 0, stream>>>(d1, dw2, db2, dw3, db3, out);
}

// Round 3
// 1844.046 us; speedup vs baseline: 11.5125x; 11.5125x over previous
//
#include <hip/hip_runtime.h>

typedef unsigned short u16;
typedef unsigned int u32;

__device__ __forceinline__ float b2f(u32 lo16) {
  union { u32 i; float f; } v; v.i = lo16 << 16; return v.f;
}
__device__ __forceinline__ u16 f2b(float f) {
  union { float f; u32 i; } v; v.f = f;
  return (u16)((v.i + 0x7fffu + ((v.i >> 16) & 1u)) >> 16);
}

// ---------------------------------------------------------------------------
// Prep: reorder weights to [ic][kh][kw][oc] (convs) / [pky][pkx][ic][tap][oc]
// (convT, tap = kyi*2+kxi, ky = pky+2*kyi), pad dw3 oc to 4; cnorm; zero loss.
// ---------------------------------------------------------------------------
__global__ void prep_k(const float* __restrict__ ew1, const float* __restrict__ ew2,
                       const float* __restrict__ ew3, const float* __restrict__ dw1,
                       const float* __restrict__ dw2, const float* __restrict__ dw3,
                       const float* __restrict__ cb,
                       float* W1, float* W2, float* W3, float* WT1, float* WT2,
                       float* W3d, float* cnorm, float* loss) {
  int tid = blockIdx.x * blockDim.x + threadIdx.x;
  int nth = gridDim.x * blockDim.x;
  for (int i = tid; i < 3*4*4*32; i += nth) {          // W1[3][4][4][32] <- ew1[32][3][4][4]
    int oc = i & 31; int r = i >> 5; int kw = r & 3; r >>= 2; int kh = r & 3; int ic = r >> 2;
    W1[i] = ew1[((oc*3 + ic)*4 + kh)*4 + kw];
  }
  for (int i = tid; i < 32*4*4*64; i += nth) {         // W2[32][4][4][64] <- ew2[64][32][4][4]
    int oc = i & 63; int r = i >> 6; int kw = r & 3; r >>= 2; int kh = r & 3; int ic = r >> 2;
    W2[i] = ew2[((oc*32 + ic)*4 + kh)*4 + kw];
  }
  for (int i = tid; i < 64*3*3*64; i += nth) {         // W3[64][3][3][64] <- ew3[64][64][3][3]
    int oc = i & 63; int r = i >> 6; int kw = r % 3; r /= 3; int kh = r % 3; int ic = r / 3;
    W3[i] = ew3[((oc*64 + ic)*3 + kh)*3 + kw];
  }
  for (int i = tid; i < 4*64*4*64; i += nth) {         // WT1[p][64][4][64] <- dw1[64][64][4][4]
    int oc = i & 63; int r = i >> 6; int tap = r & 3; r >>= 2; int ic = r & 63; int p = r >> 6;
    int ky = (p >> 1) + 2*(tap >> 1);
    int kx = (p & 1) + 2*(tap & 1);
    WT1[i] = dw1[((ic*64 + oc)*4 + ky)*4 + kx];
  }
  for (int i = tid; i < 4*64*4*32; i += nth) {         // WT2[p][64][4][32] <- dw2[64][32][4][4]
    int oc = i & 31; int r = i >> 5; int tap = r & 3; r >>= 2; int ic = r & 63; int p = r >> 6;
    int ky = (p >> 1) + 2*(tap >> 1);
    int kx = (p & 1) + 2*(tap & 1);
    WT2[i] = dw2[((ic*32 + oc)*4 + ky)*4 + kx];
  }
  for (int i = tid; i < 32*3*3*4; i += nth) {          // W3d[32][3][3][4] <- dw3[3][32][3][3]
    int oc = i & 3; int r = i >> 2; int kw = r % 3; r /= 3; int kh = r % 3; int ic = r / 3;
    W3d[i] = (oc < 3) ? dw3[((oc*32 + ic)*3 + kh)*3 + kw] : 0.f;
  }
  for (int k = tid; k < 512; k += nth) {
    float s = 0.f;
    for (int d = 0; d < 64; ++d) { float c = cb[k*64+d]; s += c*c; }
    cnorm[k] = s;
  }
  if (tid == 0) *loss = 0.f;
}

// ---------------------------------------------------------------------------
// conv1: x f32[32][3][256][256] -> h1 bf16[32][32][128][128], k4 s2 p1, relu
// tile 16x x 8y. lane: 4 pos x 4 oc.
// ---------------------------------------------------------------------------
__global__ __launch_bounds__(256) void conv1_k(
    const float* __restrict__ x, const float* __restrict__ W1,
    const float* __restrict__ b1, u16* __restrict__ h1) {
  __shared__ float ins[3*18*36];
  int Tx = blockIdx.x, Ty = blockIdx.y, b = blockIdx.z;
  int tid = threadIdx.x;
  for (int i = tid; i < 3*18*36; i += 256) {
    int c = i % 36; int r = (i / 36) % 18; int ic = i / 648;
    int iy = 16*Ty - 1 + r, ix = 32*Tx - 2 + c;
    float v = 0.f;
    if ((unsigned)iy < 256u && (unsigned)ix < 256u)
      v = x[((b*3 + ic)*256 + iy)*256 + ix];
    ins[i] = v;
  }
  __syncthreads();
  int posg = tid & 31, ocg = tid >> 5;
  int Y = posg >> 2, Xg = posg & 3;
  int oc0 = ocg * 4;
  float acc[4][4];
#pragma unroll
  for (int j = 0; j < 4; ++j) { float bv = b1[oc0+j];
#pragma unroll
    for (int e = 0; e < 4; ++e) acc[j][e] = bv; }
  for (int ic = 0; ic < 3; ++ic)
#pragma unroll
    for (int kh = 0; kh < 4; ++kh) {
      const float* row = &ins[ic*648 + (2*Y + kh)*36 + 8*Xg];
      float win[12];
#pragma unroll
      for (int t = 0; t < 12; ++t) win[t] = row[t];
#pragma unroll
      for (int kw = 0; kw < 4; ++kw) {
        const float* wp = &W1[((ic*4 + kh)*4 + kw)*32 + oc0];
        float w0 = wp[0], w1 = wp[1], w2 = wp[2], w3 = wp[3];
#pragma unroll
        for (int e = 0; e < 4; ++e) {
          float v = win[2*e + kw + 1];
          acc[0][e] += w0*v; acc[1][e] += w1*v; acc[2][e] += w2*v; acc[3][e] += w3*v;
        }
      }
    }
  int oy = 8*Ty + Y;
#pragma unroll
  for (int j = 0; j < 4; ++j) {
    u16* op = &h1[((b*32 + oc0 + j)*128 + oy)*128 + 16*Tx + 4*Xg];
#pragma unroll
    for (int e = 0; e < 4; ++e) op[e] = f2b(fmaxf(acc[j][e], 0.f));
  }
}

// ---------------------------------------------------------------------------
// conv2: h1 bf16 -> h2 bf16[32][64][64][64], k4 s2 p1, relu.
// tile 16x x 8y. lane: 4 pos x 8 oc.
// ---------------------------------------------------------------------------
__global__ __launch_bounds__(256) void conv2_k(
    const u16* __restrict__ h1, const float* __restrict__ W2,
    const float* __restrict__ b2, u16* __restrict__ h2) {
  __shared__ u16 ins[32*18*36];
  int Tx = blockIdx.x, Ty = blockIdx.y, b = blockIdx.z;
  int tid = threadIdx.x;
  for (int i = tid; i < 32*18*36; i += 256) {
    int c = i % 36; int r = (i / 36) % 18; int ic = i / 648;
    int iy = 16*Ty - 1 + r, ix = 32*Tx - 2 + c;
    u16 v = 0;
    if ((unsigned)iy < 128u && (unsigned)ix < 128u)
      v = h1[((b*32 + ic)*128 + iy)*128 + ix];
    ins[i] = v;
  }
  __syncthreads();
  int posg = tid & 31, ocg = tid >> 5;
  int Y = posg >> 2, Xg = posg & 3;
  int oc0 = ocg * 8;
  float acc[8][4];
#pragma unroll
  for (int j = 0; j < 8; ++j) { float bv = b2[oc0+j];
#pragma unroll
    for (int e = 0; e < 4; ++e) acc[j][e] = bv; }
  for (int ic = 0; ic < 32; ++ic)
#pragma unroll
    for (int kh = 0; kh < 4; ++kh) {
      const u32* row = (const u32*)&ins[ic*648 + (2*Y + kh)*36 + 8*Xg];
      float win[12];
#pragma unroll
      for (int t = 0; t < 6; ++t) {
        u32 u = row[t];
        win[2*t] = b2f(u & 0xffffu); win[2*t+1] = b2f(u >> 16);
      }
#pragma unroll
      for (int kw = 0; kw < 4; ++kw) {
        const float4* wp = (const float4*)&W2[((ic*4 + kh)*4 + kw)*64 + oc0];
        float4 wa = wp[0], wb = wp[1];
#pragma unroll
        for (int e = 0; e < 4; ++e) {
          float v = win[2*e + kw + 1];
          acc[0][e] += wa.x*v; acc[1][e] += wa.y*v; acc[2][e] += wa.z*v; acc[3][e] += wa.w*v;
          acc[4][e] += wb.x*v; acc[5][e] += wb.y*v; acc[6][e] += wb.z*v; acc[7][e] += wb.w*v;
        }
      }
    }
  int oy = 8*Ty + Y;
#pragma unroll
  for (int j = 0; j < 8; ++j) {
    u16* op = &h2[((b*64 + oc0 + j)*64 + oy)*64 + 16*Tx + 4*Xg];
#pragma unroll
    for (int e = 0; e < 4; ++e) op[e] = f2b(fmaxf(acc[j][e], 0.f));
  }
}

// ---------------------------------------------------------------------------
// conv3: h2 bf16 -> z f32[32][64][64][64], k3 s1 p1, no act.
// tile 16x x 8y. lane: 4 pos x 8 oc.
// ---------------------------------------------------------------------------
__global__ __launch_bounds__(256) void conv3_k(
    const u16* __restrict__ h2, const float* __restrict__ W3,
    const float* __restrict__ b3, float* __restrict__ z) {
  __shared__ u16 ins[64*10*20];
  int Tx = blockIdx.x, Ty = blockIdx.y, b = blockIdx.z;
  int tid = threadIdx.x;
  for (int i = tid; i < 64*10*20; i += 256) {
    int c = i % 20; int r = (i / 20) % 10; int ic = i / 200;
    int iy = 8*Ty - 1 + r, ix = 16*Tx - 2 + c;
    u16 v = 0;
    if ((unsigned)iy < 64u && (unsigned)ix < 64u)
      v = h2[((b*64 + ic)*64 + iy)*64 + ix];
    ins[i] = v;
  }
  __syncthreads();
  int posg = tid & 31, ocg = tid >> 5;
  int Y = posg >> 2, Xg = posg & 3;
  int oc0 = ocg * 8;
  float acc[8][4];
#pragma unroll
  for (int j = 0; j < 8; ++j) { float bv = b3[oc0+j];
#pragma unroll
    for (int e = 0; e < 4; ++e) acc[j][e] = bv; }
  for (int ic = 0; ic < 64; ++ic)
#pragma unroll
    for (int kh = 0; kh < 3; ++kh) {
      const u32* row = (const u32*)&ins[ic*200 + (Y + kh)*20 + 4*Xg];
      float win[8];
#pragma unroll
      for (int t = 0; t < 4; ++t) {
        u32 u = row[t];
        win[2*t] = b2f(u & 0xffffu); win[2*t+1] = b2f(u >> 16);
      }
#pragma unroll
      for (int kw = 0; kw < 3; ++kw) {
        const float4* wp = (const float4*)&W3[((ic*3 + kh)*3 + kw)*64 + oc0];
        float4 wa = wp[0], wb = wp[1];
#pragma unroll
        for (int e = 0; e < 4; ++e) {
          float v = win[e + kw + 1];
          acc[0][e] += wa.x*v; acc[1][e] += wa.y*v; acc[2][e] += wa.z*v; acc[3][e] += wa.w*v;
          acc[4][e] += wb.x*v; acc[5][e] += wb.y*v; acc[6][e] += wb.z*v; acc[7][e] += wb.w*v;
        }
      }
    }
  int oy = 8*Ty + Y;
#pragma unroll
  for (int j = 0; j < 8; ++j)
#pragma unroll
    for (int e = 0; e < 4; ++e)
      z[((b*64 + oc0 + j)*64 + oy)*64 + 16*Tx + 4*Xg + e] = acc[j][e];
}

// ---------------------------------------------------------------------------
// VQ: argmin over 512 codes per z-vector; q bf16; loss += 1.25*mean((q-z)^2).
// ---------------------------------------------------------------------------
__global__ __launch_bounds__(256) void vq_k(
    const float* __restrict__ z, const float* __restrict__ cb,
    const float* __restrict__ cnorm, u16* __restrict__ q,
    float* __restrict__ loss) {
  __shared__ float cbs[256 * 64];
  int tid = threadIdx.x;
  int n = blockIdx.x * 256 + tid;
  int b = n >> 12;
  int hw = n & 4095;
  const float* zp = z + (b << 18) + hw;
  float zr[64];
#pragma unroll
  for (int d = 0; d < 64; ++d) zr[d] = zp[d << 12];

  float best = 3.4e38f;
  int bestk = 0;
  for (int half = 0; half < 2; ++half) {
    __syncthreads();
    const float4* src = (const float4*)(cb + half * 256 * 64);
    float4* dst = (float4*)cbs;
    for (int i = tid; i < 4096; i += 256) dst[i] = src[i];
    __syncthreads();
    for (int k = 0; k < 256; ++k) {
      const float4* row = (const float4*)(cbs + k * 64);
      float a0 = 0.f, a1 = 0.f, a2 = 0.f, a3 = 0.f;
#pragma unroll
      for (int j = 0; j < 16; j += 4) {
        float4 c0 = row[j], c1 = row[j+1], c2 = row[j+2], c3 = row[j+3];
        a0 += c0.x*zr[4*j+0] + c0.y*zr[4*j+1] + c0.z*zr[4*j+2] + c0.w*zr[4*j+3];
        a1 += c1.x*zr[4*j+4] + c1.y*zr[4*j+5] + c1.z*zr[4*j+6] + c1.w*zr[4*j+7];
        a2 += c2.x*zr[4*j+8] + c2.y*zr[4*j+9] + c2.z*zr[4*j+10] + c2.w*zr[4*j+11];
        a3 += c3.x*zr[4*j+12] + c3.y*zr[4*j+13] + c3.z*zr[4*j+14] + c3.w*zr[4*j+15];
      }
      float dist = cnorm[half*256 + k] - 2.f * ((a0+a1) + (a2+a3));
      if (dist < best) { best = dist; bestk = half*256 + k; }
    }
  }
  const float* crow = cb + bestk * 64;
  u16* qp = q + (b << 18) + hw;
  float lsum = 0.f;
#pragma unroll
  for (int d = 0; d < 64; ++d) {
    float c = crow[d];
    float diff = c - zr[d];
    lsum += diff * diff;
    qp[d << 12] = f2b(c);
  }
  __syncthreads();
  cbs[tid] = lsum;
  __syncthreads();
  for (int s = 128; s > 0; s >>= 1) {
    if (tid < s) cbs[tid] += cbs[tid + s];
    __syncthreads();
  }
  if (tid == 0) atomicAdd(loss, cbs[0] * (1.25f / 8388608.f));
}

// ---------------------------------------------------------------------------
// convT1: q bf16[32][64][64][64] -> d1 bf16[32][64][128][128], k4 s2 p1, relu.
// Parity decomposition: wave w handles parity (a=w&1, bp=w>>1) of 16x16 tile.
// lane: 4 pos x 16 oc.
// ---------------------------------------------------------------------------
__global__ __launch_bounds__(256) void convt1_k(
    const u16* __restrict__ q, const float* __restrict__ WT1,
    const float* __restrict__ b1, u16* __restrict__ d1) {
  __shared__ u16 qs[64*10*10];
  int Tx = blockIdx.x, Ty = blockIdx.y, b = blockIdx.z;
  int tid = threadIdx.x;
  for (int i = tid; i < 64*10*10; i += 256) {
    int c = i % 10; int r = (i / 10) % 10; int ic = i / 100;
    int iy = 8*Ty - 1 + r, ix = 8*Tx - 1 + c;
    u16 v = 0;
    if ((unsigned)iy < 64u && (unsigned)ix < 64u)
      v = q[((b*64 + ic)*64 + iy)*64 + ix];
    qs[i] = v;
  }
  __syncthreads();
  int w = tid >> 6;
  int a = w & 1, bp = w >> 1;
  int l = tid & 63;
  int posg = l & 15, ocg = l >> 4;
  int Y = posg >> 1, Xg = posg & 1;
  int oc0 = ocg * 16;
  const float* wbase = WT1 + (((1-a)*2 + (1-bp))*64*4)*64 + oc0;
  float acc[16][4];
#pragma unroll
  for (int j = 0; j < 16; ++j) { float bv = b1[oc0+j];
#pragma unroll
    for (int e = 0; e < 4; ++e) acc[j][e] = bv; }
  int riy0 = Y + a + 1, riy1 = Y + a;
  int xoff = 4*Xg + bp;
  for (int ic = 0; ic < 64; ++ic) {
    const u16* rA = &qs[ic*100 + riy0*10 + xoff];
    const u16* rB = &qs[ic*100 + riy1*10 + xoff];
    float va[5], vb[5];
#pragma unroll
    for (int t = 0; t < 5; ++t) { va[t] = b2f(rA[t]); vb[t] = b2f(rB[t]); }
    const float* wp = wbase + ic*4*64;
#pragma unroll
    for (int tap = 0; tap < 4; ++tap) {
      const float4* w4 = (const float4*)(wp + tap*64);
      float4 wv0 = w4[0], wv1 = w4[1], wv2 = w4[2], wv3 = w4[3];
      float wr[16] = {wv0.x,wv0.y,wv0.z,wv0.w, wv1.x,wv1.y,wv1.z,wv1.w,
                      wv2.x,wv2.y,wv2.z,wv2.w, wv3.x,wv3.y,wv3.z,wv3.w};
#pragma unroll
      for (int e = 0; e < 4; ++e) {
        float v = (tap < 2) ? ((tap & 1) ? va[e] : va[e+1])
                            : ((tap & 1) ? vb[e] : vb[e+1]);
#pragma unroll
        for (int j = 0; j < 16; ++j) acc[j][e] += wr[j] * v;
      }
    }
  }
  int yy = 2*Y + a;
  int ay = 16*Ty + yy;
#pragma unroll
  for (int j = 0; j < 16; ++j) {
    u16* op = &d1[((b*64 + oc0 + j)*128 + ay)*128 + 16*Tx];
#pragma unroll
    for (int e = 0; e < 4; ++e) {
      int xx = 2*(4*Xg + e) + bp;
      op[xx] = f2b(fmaxf(acc[j][e], 0.f));
    }
  }
}

// ---------------------------------------------------------------------------
// Fused tail: d2 = relu(convT(d1,w2,b2)) into LDS (16x16 tile, parity waves),
// then out = sigmoid(conv3x3(d2, W3d, b3)) on the inner 14x14.
// ---------------------------------------------------------------------------
__global__ __launch_bounds__(256) void tail_k(
    const u16* __restrict__ d1, const float* __restrict__ WT2,
    const float* __restrict__ b2, const float* __restrict__ W3d,
    const float* __restrict__ b3, float* __restrict__ out) {
  __shared__ u16 d1s[64*9*10];
  __shared__ u16 d2s[32*16*16];
  int Tx = blockIdx.x, Ty = blockIdx.y, b = blockIdx.z;
  int tid = threadIdx.x;
  for (int i = tid; i < 64*9*10; i += 256) {
    int c = i % 10; int r = (i / 10) % 9; int ic = i / 90;
    int iy = 7*Ty - 1 + r, ix = 7*Tx - 1 + c;
    u16 v = 0;
    if ((unsigned)iy < 128u && (unsigned)ix < 128u)
      v = d1[((b*64 + ic)*128 + iy)*128 + ix];
    d1s[i] = v;
  }
  __syncthreads();
  {
    int w = tid >> 6;
    int a = w & 1, bp = w >> 1;
    int l = tid & 63;
    int posg = l & 15, cg = l >> 4;
    int Y = posg >> 1, Xg = posg & 1;
    int c20 = cg * 8;
    const float* wbase = WT2 + ((a*2 + bp)*64*4)*32 + c20;
    float acc[8][4];
#pragma unroll
    for (int j = 0; j < 8; ++j) { float bv = b2[c20+j];
#pragma unroll
      for (int e = 0; e < 4; ++e) acc[j][e] = bv; }
    int rA = Y + 1, rB = Y;
    for (int ic = 0; ic < 64; ++ic) {
      const u32* rowA = (const u32*)&d1s[ic*90 + rA*10 + 4*Xg];
      const u32* rowB = (const u32*)&d1s[ic*90 + rB*10 + 4*Xg];
      float va[6], vb[6];
#pragma unroll
      for (int t = 0; t < 3; ++t) {
        u32 u = rowA[t]; va[2*t] = b2f(u & 0xffffu); va[2*t+1] = b2f(u >> 16);
        u32 u2 = rowB[t]; vb[2*t] = b2f(u2 & 0xffffu); vb[2*t+1] = b2f(u2 >> 16);
      }
      const float* wp = wbase + ic*4*32;
#pragma unroll
      for (int tap = 0; tap < 4; ++tap) {
        const float4* w4 = (const float4*)(wp + tap*32);
        float4 wA = w4[0], wB = w4[1];
        float wr[8] = {wA.x,wA.y,wA.z,wA.w, wB.x,wB.y,wB.z,wB.w};
#pragma unroll
        for (int e = 0; e < 4; ++e) {
          float v = (tap < 2) ? ((tap & 1) ? va[e] : va[e+1])
                              : ((tap & 1) ? vb[e] : vb[e+1]);
#pragma unroll
          for (int j = 0; j < 8; ++j) acc[j][e] += wr[j] * v;
        }
      }
    }
    int yy = 2*Y + a;
    int ay = 14*Ty - 1 + yy;
    int axb = 14*Tx - 1;
#pragma unroll
    for (int j = 0; j < 8; ++j)
#pragma unroll
      for (int e = 0; e < 4; ++e) {
        int xx = 2*(4*Xg + e) + bp;
        float v = fmaxf(acc[j][e], 0.f);
        if ((unsigned)ay >= 256u || (unsigned)(axb + xx) >= 256u) v = 0.f;
        d2s[((c20 + j)*16 + yy)*16 + xx] = f2b(v);
      }
  }
  __syncthreads();
  for (int p = tid; p < 196; p += 256) {
    int y = p / 14, xo = p % 14;
    int oy = 14*Ty + y, ox = 14*Tx + xo;
    if (oy >= 256 || ox >= 256) continue;
    float a0 = b3[0], a1 = b3[1], a2 = b3[2];
    for (int ic = 0; ic < 32; ++ic)
#pragma unroll
      for (int kh = 0; kh < 3; ++kh) {
        const u16* dr = &d2s[(ic*16 + y + kh)*16 + xo];
#pragma unroll
        for (int kw = 0; kw < 3; ++kw) {
          float v = b2f(dr[kw]);
          float4 wv = *(const float4*)&W3d[((ic*3 + kh)*3 + kw)*4];
          a0 += wv.x * v; a1 += wv.y * v; a2 += wv.z * v;
        }
      }
    out[((b*3 + 0)*256 + oy)*256 + ox] = 1.f/(1.f+expf(-a0));
    out[((b*3 + 1)*256 + oy)*256 + ox] = 1.f/(1.f+expf(-a1));
    out[((b*3 + 2)*256 + oy)*256 + ox] = 1.f/(1.f+expf(-a2));
  }
}

extern "C" void kernel_launch(void* const* d_in, const int* in_sizes, int n_in,
                              void* d_out, int out_size, void* d_ws, size_t ws_size,
                              hipStream_t stream) {
  const float* x   = (const float*)d_in[0];
  const float* ew1 = (const float*)d_in[1];
  const float* eb1 = (const float*)d_in[2];
  const float* ew2 = (const float*)d_in[3];
  const float* eb2 = (const float*)d_in[4];
  const float* ew3 = (const float*)d_in[5];
  const float* eb3 = (const float*)d_in[6];
  const float* cb  = (const float*)d_in[7];
  const float* dw1 = (const float*)d_in[8];
  const float* db1 = (const float*)d_in[9];
  const float* dw2 = (const float*)d_in[10];
  const float* db2 = (const float*)d_in[11];
  const float* dw3 = (const float*)d_in[12];
  const float* db3 = (const float*)d_in[13];
  float* out = (float*)d_out;

  // ws layout (bytes). Liveness: h2/q share [0,16M); h1/z/d1 share [16M,80M).
  char* ws = (char*)d_ws;
  u16*   h2 = (u16*)ws;                                 // [0, 16MiB)
  u16*   q  = (u16*)ws;                                 // after h2 dead
  u16*   h1 = (u16*)(ws + 16777216);                    // [16MiB, 48MiB)
  float* z  = (float*)(ws + 16777216);                  // after h1 dead
  u16*   d1 = (u16*)(ws + 16777216);                    // after z dead (64MiB)
  const size_t WOFF = 83886080;                         // 80 MiB
  float* WT1  = (float*)(ws + WOFF);
  float* WT2  = (float*)(ws + WOFF + 262144);
  float* W2   = (float*)(ws + WOFF + 393216);
  float* W3   = (float*)(ws + WOFF + 524288);
  float* W1   = (float*)(ws + WOFF + 671744);
  float* W3d  = (float*)(ws + WOFF + 677888);
  float* cnorm= (float*)(ws + WOFF + 682496);
  float* loss = out + 6291456;

  prep_k<<<64, 256, 0, stream>>>(ew1, ew2, ew3, dw1, dw2, dw3, cb,
                                 W1, W2, W3, WT1, WT2, W3d, cnorm, loss);
  conv1_k<<<dim3(8, 16, 32), 256, 0, stream>>>(x, W1, eb1, h1);
  conv2_k<<<dim3(4, 8, 32), 256, 0, stream>>>(h1, W2, eb2, h2);
  conv3_k<<<dim3(4, 8, 32), 256, 0, stream>>>(h2, W3, eb3, z);
  vq_k<<<512, 256, 0, stream>>>(z, cb, cnorm, q, loss);
  convt1_k<<<dim3(8, 8, 32), 256, 0, stream>>>(q, WT1, db1, d1);
  tail_k<<<dim3(19, 19, 32), 256, 0, stream>>>(d1, WT2, db2, W3d, db3, out);
}

// Round 4
// 320.624 us; speedup vs baseline: 66.2132x; 5.7514x over previous
//
#include <hip/hip_runtime.h>

typedef unsigned short u16;
typedef unsigned int u32;
typedef __attribute__((ext_vector_type(8))) short bf16x8;
typedef __attribute__((ext_vector_type(4))) float f32x4;

#define MFMA(a, b, c) __builtin_amdgcn_mfma_f32_16x16x32_bf16(a, b, c, 0, 0, 0)

__device__ __forceinline__ float b2f(u32 lo16) {
  union { u32 i; float f; } v; v.i = lo16 << 16; return v.f;
}
__device__ __forceinline__ u16 f2b(float f) {
  union { float f; u32 i; } v; v.f = f;
  return (u16)((v.i + 0x7fffu + ((v.i >> 16) & 1u)) >> 16);
}
__device__ __forceinline__ bf16x8 ld8(const u16* p) { return *(const bf16x8*)p; }

// ---------------------------------------------------------------------------
// prep: pack weights into MFMA B-fragment order, cnorm, zero loss.
// B-frag convention: frag f stored as [64 lanes][8], elem j of lane l = 
// W[k = 8*(l>>4)+j (within 32-k chunk)][n = 16*(frag n-tile) + (l&15)].
// ---------------------------------------------------------------------------
__global__ void prep_k(const float* __restrict__ ew1, const float* __restrict__ ew2,
                       const float* __restrict__ ew3, const float* __restrict__ dw1,
                       const float* __restrict__ dw2, const float* __restrict__ dw3,
                       const float* __restrict__ cb,
                       float* W1, u16* Bp2, u16* Bp3, u16* BpT1, u16* BpT2,
                       u16* Bpd3, u16* Bpvq, float* cnorm, float* loss) {
  int tid = blockIdx.x * blockDim.x + threadIdx.x;
  int nth = gridDim.x * blockDim.x;
  for (int i = tid; i < 1536; i += nth) {  // W1[3][4][4][32] f32 <- ew1[32][3][4][4]
    int oc = i & 31; int r = i >> 5; int kw = r & 3; r >>= 2; int kh = r & 3; int ic = r >> 2;
    W1[i] = ew1[((oc*3 + ic)*4 + kh)*4 + kw];
  }
  for (int i = tid; i < 32768; i += nth) {  // Bp2[t16][nt4][l][8] <- ew2[64][32][4][4]
    int j = i & 7, li = (i >> 3) & 63, nt = (i >> 9) & 3, t = i >> 11;
    int ic = 8*(li >> 4) + j, oc = 16*nt + (li & 15), kh = t >> 2, kw = t & 3;
    Bp2[i] = f2b(ew2[((oc*32 + ic)*4 + kh)*4 + kw]);
  }
  for (int i = tid; i < 36864; i += nth) {  // Bp3[t9][kc2][nt4][l][8] <- ew3[64][64][3][3]
    int j = i & 7, li = (i >> 3) & 63, nt = (i >> 9) & 3, kc = (i >> 11) & 1, t = i >> 12;
    int ic = 32*kc + 8*(li >> 4) + j, oc = 16*nt + (li & 15), kh = t / 3, kw = t % 3;
    Bp3[i] = f2b(ew3[((oc*64 + ic)*3 + kh)*3 + kw]);
  }
  for (int i = tid; i < 65536; i += nth) {  // BpT1[p4][t4][kc2][nt4][l][8] <- dw1[64][64][4][4]
    int j = i & 7, li = (i >> 3) & 63, nt = (i >> 9) & 3, kc = (i >> 11) & 1,
        t = (i >> 12) & 3, p = i >> 14;
    int a = p >> 1, b = p & 1;
    int ky = (1 - a) + 2*(t >> 1), kx = (1 - b) + 2*(t & 1);
    int ic = 32*kc + 8*(li >> 4) + j, oc = 16*nt + (li & 15);
    BpT1[i] = f2b(dw1[((ic*64 + oc)*4 + ky)*4 + kx]);
  }
  for (int i = tid; i < 32768; i += nth) {  // BpT2[p4][t4][kc2][nt2][l][8] <- dw2[64][32][4][4]
    int j = i & 7, li = (i >> 3) & 63, nt = (i >> 9) & 1, kc = (i >> 10) & 1,
        t = (i >> 11) & 3, p = i >> 13;
    int a = p >> 1, b = p & 1;
    int ky = (1 - a) + 2*(t >> 1), kx = (1 - b) + 2*(t & 1);
    int ic = 32*kc + 8*(li >> 4) + j, oc = 16*nt + (li & 15);
    BpT2[i] = f2b(dw2[((ic*32 + oc)*4 + ky)*4 + kx]);
  }
  for (int i = tid; i < 4608; i += nth) {  // Bpd3[t9][l][8] <- dw3[3][32][3][3], n padded to 16
    int j = i & 7, li = (i >> 3) & 63, t = i >> 9;
    int n = li & 15, ic = 8*(li >> 4) + j, kh = t / 3, kw = t % 3;
    Bpd3[i] = (n < 3) ? f2b(dw3[((n*32 + ic)*3 + kh)*3 + kw]) : (u16)0;
  }
  for (int i = tid; i < 32768; i += nth) {  // Bpvq[kc2][nt32][l][8] <- cb[512][64]
    int j = i & 7, li = (i >> 3) & 63, nt = (i >> 9) & 31, kc = i >> 14;
    int d = 32*kc + 8*(li >> 4) + j, code = 16*nt + (li & 15);
    Bpvq[i] = f2b(cb[code*64 + d]);
  }
  for (int k = tid; k < 512; k += nth) {
    float s = 0.f;
    for (int d = 0; d < 64; ++d) { float c = cb[k*64 + d]; s += c*c; }
    cnorm[k] = s;
  }
  if (tid == 0) *loss = 0.f;
}

// ---------------------------------------------------------------------------
// conv1 (VALU): x f32 NCHW[32][3][256][256] -> h1 bf16 NHWC[32][128][128][32]
// k4 s2 p1 relu. tile 16ox x 8oy; lane: 4 pos x 4 oc.
// ---------------------------------------------------------------------------
__global__ __launch_bounds__(256) void conv1_k(
    const float* __restrict__ x, const float* __restrict__ W1,
    const float* __restrict__ b1, u16* __restrict__ h1) {
  __shared__ float ins[3*18*36];
  int Tx = blockIdx.x, Ty = blockIdx.y, b = blockIdx.z;
  int tid = threadIdx.x;
  for (int i = tid; i < 3*18*36; i += 256) {
    int c = i % 36; int r = (i / 36) % 18; int ic = i / 648;
    int iy = 16*Ty - 1 + r, ix = 32*Tx - 2 + c;
    float v = 0.f;
    if ((unsigned)iy < 256u && (unsigned)ix < 256u)
      v = x[((size_t)(b*3 + ic)*256 + iy)*256 + ix];
    ins[i] = v;
  }
  __syncthreads();
  int posg = tid & 31, ocg = tid >> 5;
  int Y = posg >> 2, Xg = posg & 3;
  int oc0 = ocg * 4;
  float acc[4][4];
#pragma unroll
  for (int j = 0; j < 4; ++j) { float bv = b1[oc0 + j];
#pragma unroll
    for (int e = 0; e < 4; ++e) acc[j][e] = bv; }
  for (int ic = 0; ic < 3; ++ic)
#pragma unroll
    for (int kh = 0; kh < 4; ++kh) {
      const float* row = &ins[ic*648 + (2*Y + kh)*36 + 8*Xg];
      float win[12];
#pragma unroll
      for (int t = 0; t < 12; ++t) win[t] = row[t];
#pragma unroll
      for (int kw = 0; kw < 4; ++kw) {
        const float* wp = &W1[((ic*4 + kh)*4 + kw)*32 + oc0];
        float w0 = wp[0], w1 = wp[1], w2 = wp[2], w3 = wp[3];
#pragma unroll
        for (int e = 0; e < 4; ++e) {
          float v = win[2*e + kw + 1];
          acc[0][e] += w0*v; acc[1][e] += w1*v; acc[2][e] += w2*v; acc[3][e] += w3*v;
        }
      }
    }
  int oy = 8*Ty + Y;
  int oxb = 16*Tx + 4*Xg;
#pragma unroll
  for (int e = 0; e < 4; ++e) {
    u16* op = &h1[((size_t)(b*128 + oy)*128 + oxb + e)*32 + oc0];
#pragma unroll
    for (int j = 0; j < 4; ++j) op[j] = f2b(fmaxf(acc[j][e], 0.f));
  }
}

// ---------------------------------------------------------------------------
// conv2 (MFMA): h1 NHWC -> h2 bf16 NHWC[32][64][64][64], k4 s2 p1 relu.
// Block: 16ox x 8oy x 64oc. Wave w: oy rows {w, w+4}, all 4 oc-tiles.
// ---------------------------------------------------------------------------
__global__ __launch_bounds__(256) void conv2_k(
    const u16* __restrict__ h1, const u16* __restrict__ Bp2,
    const float* __restrict__ eb2, u16* __restrict__ h2) {
  __shared__ u16 lds[2448*8];  // [row18][c4][x34][8]
  int Tx = blockIdx.x, Ty = blockIdx.y, img = blockIdx.z;
  int tid = threadIdx.x;
  for (int i = tid; i < 2448; i += 256) {
    int c = i & 3; int x = (i >> 2) % 34; int row = (i >> 2) / 34;
    int iy = 16*Ty - 1 + row, ix = 32*Tx - 1 + x;
    f32x4 v = {0,0,0,0};
    if ((unsigned)iy < 128u && (unsigned)ix < 128u)
      v = *(const f32x4*)(h1 + (((size_t)(img*128 + iy)*128 + ix)*32 + c*8));
    *(f32x4*)(lds + ((row*4 + c)*34 + x)*8) = v;
  }
  __syncthreads();
  int w = tid >> 6, l = tid & 63, lg = l >> 4, lc = l & 15;
  f32x4 acc[2][4];
#pragma unroll
  for (int nt = 0; nt < 4; ++nt) {
    float bv = eb2[nt*16 + lc];
    acc[0][nt] = (f32x4){bv,bv,bv,bv}; acc[1][nt] = (f32x4){bv,bv,bv,bv};
  }
#pragma unroll
  for (int t = 0; t < 16; ++t) {
    int kh = t >> 2, kw = t & 3;
    bf16x8 a0 = ld8(lds + (((2*w + kh)*4 + lg)*34 + 2*lc + kw)*8);
    bf16x8 a1 = ld8(lds + (((2*(w+4) + kh)*4 + lg)*34 + 2*lc + kw)*8);
    const u16* bp = Bp2 + t*2048 + l*8;
    bf16x8 b0 = ld8(bp), b1 = ld8(bp + 512), b2v = ld8(bp + 1024), b3v = ld8(bp + 1536);
    acc[0][0] = MFMA(a0, b0, acc[0][0]); acc[0][1] = MFMA(a0, b1, acc[0][1]);
    acc[0][2] = MFMA(a0, b2v, acc[0][2]); acc[0][3] = MFMA(a0, b3v, acc[0][3]);
    acc[1][0] = MFMA(a1, b0, acc[1][0]); acc[1][1] = MFMA(a1, b1, acc[1][1]);
    acc[1][2] = MFMA(a1, b2v, acc[1][2]); acc[1][3] = MFMA(a1, b3v, acc[1][3]);
  }
#pragma unroll
  for (int m = 0; m < 2; ++m) {
    int oy = 8*Ty + w + m*4;
#pragma unroll
    for (int nt = 0; nt < 4; ++nt)
#pragma unroll
      for (int r = 0; r < 4; ++r) {
        int e = 4*lg + r;
        h2[((size_t)(img*64 + oy)*64 + 16*Tx + e)*64 + nt*16 + lc] =
            f2b(fmaxf(acc[m][nt][r], 0.f));
      }
  }
}

// ---------------------------------------------------------------------------
// conv3 enc (MFMA): h2 NHWC -> z bf16 NHWC[32][64][64][64], k3 s1 p1, no act.
// ---------------------------------------------------------------------------
__global__ __launch_bounds__(256) void conv3e_k(
    const u16* __restrict__ h2, const u16* __restrict__ Bp3,
    const float* __restrict__ eb3, u16* __restrict__ z) {
  __shared__ u16 lds[1440*8];  // [row10][c8][x18][8]
  int Tx = blockIdx.x, Ty = blockIdx.y, img = blockIdx.z;
  int tid = threadIdx.x;
  for (int i = tid; i < 1440; i += 256) {
    int c = i & 7; int x = (i >> 3) % 18; int row = (i >> 3) / 18;
    int iy = 8*Ty - 1 + row, ix = 16*Tx - 1 + x;
    f32x4 v = {0,0,0,0};
    if ((unsigned)iy < 64u && (unsigned)ix < 64u)
      v = *(const f32x4*)(h2 + (((size_t)(img*64 + iy)*64 + ix)*64 + c*8));
    *(f32x4*)(lds + ((row*8 + c)*18 + x)*8) = v;
  }
  __syncthreads();
  int w = tid >> 6, l = tid & 63, lg = l >> 4, lc = l & 15;
  f32x4 acc[2][4];
#pragma unroll
  for (int nt = 0; nt < 4; ++nt) {
    float bv = eb3[nt*16 + lc];
    acc[0][nt] = (f32x4){bv,bv,bv,bv}; acc[1][nt] = (f32x4){bv,bv,bv,bv};
  }
#pragma unroll
  for (int t = 0; t < 9; ++t) {
    int kh = t / 3, kw = t % 3;
#pragma unroll
    for (int kc = 0; kc < 2; ++kc) {
      bf16x8 a0 = ld8(lds + (((w + kh)*8 + kc*4 + lg)*18 + lc + kw)*8);
      bf16x8 a1 = ld8(lds + (((w + 4 + kh)*8 + kc*4 + lg)*18 + lc + kw)*8);
      const u16* bp = Bp3 + (t*2 + kc)*2048 + l*8;
      bf16x8 b0 = ld8(bp), b1 = ld8(bp + 512), b2v = ld8(bp + 1024), b3v = ld8(bp + 1536);
      acc[0][0] = MFMA(a0, b0, acc[0][0]); acc[0][1] = MFMA(a0, b1, acc[0][1]);
      acc[0][2] = MFMA(a0, b2v, acc[0][2]); acc[0][3] = MFMA(a0, b3v, acc[0][3]);
      acc[1][0] = MFMA(a1, b0, acc[1][0]); acc[1][1] = MFMA(a1, b1, acc[1][1]);
      acc[1][2] = MFMA(a1, b2v, acc[1][2]); acc[1][3] = MFMA(a1, b3v, acc[1][3]);
    }
  }
#pragma unroll
  for (int m = 0; m < 2; ++m) {
    int oy = 8*Ty + w + m*4;
#pragma unroll
    for (int nt = 0; nt < 4; ++nt)
#pragma unroll
      for (int r = 0; r < 4; ++r) {
        int e = 4*lg + r;
        z[((size_t)(img*64 + oy)*64 + 16*Tx + e)*64 + nt*16 + lc] = f2b(acc[m][nt][r]);
      }
  }
}

// ---------------------------------------------------------------------------
// VQ (MFMA): z bf16 NHWC -> q bf16 NHWC + loss. M=131072, N=512, K=64.
// ---------------------------------------------------------------------------
__global__ __launch_bounds__(256) void vqm_k(
    const u16* __restrict__ z, const u16* __restrict__ Bpvq,
    const float* __restrict__ cnorm, const float* __restrict__ cbf,
    u16* __restrict__ q, float* __restrict__ loss) {
  __shared__ u16 cbl[32768];
  __shared__ float cnl[512];
  __shared__ int idxl[64];
  __shared__ float red[256];
  int tid = threadIdx.x;
  for (int i = tid; i < 4096; i += 256)
    *(f32x4*)(cbl + i*8) = *(const f32x4*)(Bpvq + i*8);
  for (int i = tid; i < 512; i += 256) cnl[i] = cnorm[i];
  __syncthreads();
  int w = tid >> 6, l = tid & 63, lg = l >> 4, lc = l & 15;
  int wglobal = blockIdx.x*4 + w;
  float lsum = 0.f;
  for (int it = 0; it < 8; ++it) {
    int mf = wglobal + it*1024;
    size_t P = (size_t)mf * 16;
    bf16x8 a0 = ld8(z + (P + lc)*64 + lg*8);
    bf16x8 a1 = ld8(z + (P + lc)*64 + 32 + lg*8);
    float best[4] = {1e30f, 1e30f, 1e30f, 1e30f};
    int bidx[4] = {0, 0, 0, 0};
    for (int nt = 0; nt < 32; ++nt) {
      f32x4 acc = {0,0,0,0};
      acc = MFMA(a0, ld8(cbl + (nt*64 + l)*8), acc);
      acc = MFMA(a1, ld8(cbl + ((32 + nt)*64 + l)*8), acc);
      float cn = cnl[nt*16 + lc];
      int code = nt*16 + lc;
#pragma unroll
      for (int r = 0; r < 4; ++r) {
        float dist = cn - 2.f*acc[r];
        if (dist < best[r]) { best[r] = dist; bidx[r] = code; }
      }
    }
#pragma unroll
    for (int r = 0; r < 4; ++r) {
      float b = best[r]; int bi = bidx[r];
      for (int m = 1; m < 16; m <<= 1) {
        float ob = __shfl_xor(b, m);
        int oi = __shfl_xor(bi, m);
        if (ob < b || (ob == b && oi < bi)) { b = ob; bi = oi; }
      }
      if (lc == 0) idxl[w*16 + lg*4 + r] = bi;
    }
    int m = lc, ch0 = lg*16;
    int id = idxl[w*16 + m];
    const float* crow = cbf + (size_t)id*64 + ch0;
    const u16* zp = z + (P + m)*64 + ch0;
    u32* qp = (u32*)(q + (P + m)*64 + ch0);
#pragma unroll
    for (int c = 0; c < 16; c += 2) {
      float c0 = crow[c], c1 = crow[c+1];
      float d0 = c0 - b2f(zp[c]), d1 = c1 - b2f(zp[c+1]);
      lsum += d0*d0 + d1*d1;
      qp[c >> 1] = (u32)f2b(c0) | ((u32)f2b(c1) << 16);
    }
  }
  red[tid] = lsum;
  __syncthreads();
  for (int s = 128; s > 0; s >>= 1) {
    if (tid < s) red[tid] += red[tid + s];
    __syncthreads();
  }
  if (tid == 0) atomicAdd(loss, red[0] * (1.25f / 8388608.f));
}

// ---------------------------------------------------------------------------
// convT1 (MFMA, parity): q NHWC -> d1 bf16 NHWC[32][128][128][64], k4 s2 p1 relu.
// 4 waves = 4 parities (a,b). Wave: 4 py rows x 16 px x 64 oc, K=256.
// ---------------------------------------------------------------------------
__global__ __launch_bounds__(256) void convt1_k(
    const u16* __restrict__ q, const u16* __restrict__ BpT1,
    const float* __restrict__ db1, u16* __restrict__ d1) {
  __shared__ u16 lds[864*8];  // [row6][c8][x18][8]
  int Tx = blockIdx.x, Ty = blockIdx.y, img = blockIdx.z;
  int X0 = 16*Tx, P0 = 4*Ty;
  int tid = threadIdx.x;
  for (int i = tid; i < 864; i += 256) {
    int c = i & 7; int x = (i >> 3) % 18; int row = (i >> 3) / 18;
    int iy = P0 - 1 + row, ix = X0 - 1 + x;
    f32x4 v = {0,0,0,0};
    if ((unsigned)iy < 64u && (unsigned)ix < 64u)
      v = *(const f32x4*)(q + (((size_t)(img*64 + iy)*64 + ix)*64 + c*8));
    *(f32x4*)(lds + ((row*8 + c)*18 + x)*8) = v;
  }
  __syncthreads();
  int w = tid >> 6, l = tid & 63, lg = l >> 4, lc = l & 15;
  int a = w & 1, bp_ = w >> 1;
  f32x4 acc[4][4];
#pragma unroll
  for (int nt = 0; nt < 4; ++nt) {
    float bv = db1[nt*16 + lc];
#pragma unroll
    for (int m = 0; m < 4; ++m) acc[m][nt] = (f32x4){bv,bv,bv,bv};
  }
  const u16* bbase = BpT1 + (size_t)(a*2 + bp_)*16384;
#pragma unroll
  for (int t = 0; t < 4; ++t) {
    int kyi = t >> 1, kxi = t & 1;
#pragma unroll
    for (int kc = 0; kc < 2; ++kc) {
      const u16* bp = bbase + (t*2 + kc)*2048 + l*8;
      bf16x8 b0 = ld8(bp), b1 = ld8(bp + 512), b2v = ld8(bp + 1024), b3v = ld8(bp + 1536);
      int xg = lc + bp_ - kxi + 1;
#pragma unroll
      for (int m = 0; m < 4; ++m) {
        int rowg = m + a - kyi + 1;
        bf16x8 av = ld8(lds + ((rowg*8 + kc*4 + lg)*18 + xg)*8);
        acc[m][0] = MFMA(av, b0, acc[m][0]);
        acc[m][1] = MFMA(av, b1, acc[m][1]);
        acc[m][2] = MFMA(av, b2v, acc[m][2]);
        acc[m][3] = MFMA(av, b3v, acc[m][3]);
      }
    }
  }
#pragma unroll
  for (int m = 0; m < 4; ++m) {
    int oy = 2*(P0 + m) + a;
#pragma unroll
    for (int nt = 0; nt < 4; ++nt)
#pragma unroll
      for (int r = 0; r < 4; ++r) {
        int e = 4*lg + r;
        int ox = 2*(X0 + e) + bp_;
        d1[((size_t)(img*128 + oy)*128 + ox)*64 + nt*16 + lc] =
            f2b(fmaxf(acc[m][nt][r], 0.f));
      }
  }
}

// ---------------------------------------------------------------------------
// tail (MFMA): d2 = relu(convT2(d1)) into LDS (32x16 d2 tile, parity waves),
// then out = sigmoid(conv3x3(d2)) on 30x14 interior. out f32 NCHW.
// ---------------------------------------------------------------------------
__global__ __launch_bounds__(256) void tail_k(
    const u16* __restrict__ d1, const u16* __restrict__ BpT2,
    const float* __restrict__ db2, const u16* __restrict__ Bpd3,
    const float* __restrict__ db3, float* __restrict__ out) {
  __shared__ u16 lds[1440*8];   // d1 halo [row10][c8][x18][8]
  __shared__ u16 d2s[2048*8];   // [ly16][c4][lx32][8]
  __shared__ u16 b3l[4608];
  int Tx = blockIdx.x, Ty = blockIdx.y, img = blockIdx.z;
  int DX0 = 30*Tx - 1, DY0 = 14*Ty - 1;
  int IY0 = (DY0 - 2) >> 1, IX0 = (DX0 - 2) >> 1;
  int tid = threadIdx.x;
  for (int i = tid; i < 1440; i += 256) {
    int c = i & 7; int x = (i >> 3) % 18; int row = (i >> 3) / 18;
    int iy = IY0 + row, ix = IX0 + x;
    f32x4 v = {0,0,0,0};
    if ((unsigned)iy < 128u && (unsigned)ix < 128u)
      v = *(const f32x4*)(d1 + (((size_t)(img*128 + iy)*128 + ix)*64 + c*8));
    *(f32x4*)(lds + ((row*8 + c)*18 + x)*8) = v;
  }
  for (int i = tid; i < 576; i += 256)
    *(f32x4*)(b3l + i*8) = *(const f32x4*)(Bpd3 + i*8);
  __syncthreads();
  int w = tid >> 6, l = tid & 63, lg = l >> 4, lc = l & 15;
  {
    int a = w & 1, bp_ = w >> 1;
    int py0 = (DY0 + ((DY0 ^ a) & 1)) >> 1;
    int px0 = (DX0 + ((DX0 ^ bp_) & 1)) >> 1;
    f32x4 acc[8][2];
#pragma unroll
    for (int nt = 0; nt < 2; ++nt) {
      float bv = db2[nt*16 + lc];
#pragma unroll
      for (int m = 0; m < 8; ++m) acc[m][nt] = (f32x4){bv,bv,bv,bv};
    }
    const u16* bbase = BpT2 + (size_t)(a*2 + bp_)*8192;
#pragma unroll
    for (int t = 0; t < 4; ++t) {
      int kyi = t >> 1, kxi = t & 1;
#pragma unroll
      for (int kc = 0; kc < 2; ++kc) {
        const u16* bb = bbase + (t*2 + kc)*1024 + l*8;
        bf16x8 b0 = ld8(bb), b1 = ld8(bb + 512);
        int xg = (px0 + lc) + bp_ - kxi - IX0;
#pragma unroll
        for (int m = 0; m < 8; ++m) {
          int rowg = (py0 + m) + a - kyi - IY0;
          bf16x8 av = ld8(lds + ((rowg*8 + kc*4 + lg)*18 + xg)*8);
          acc[m][0] = MFMA(av, b0, acc[m][0]);
          acc[m][1] = MFMA(av, b1, acc[m][1]);
        }
      }
    }
#pragma unroll
    for (int m = 0; m < 8; ++m) {
      int py = py0 + m; int oy = 2*py + a;
      int ly = oy - DY0;
#pragma unroll
      for (int nt = 0; nt < 2; ++nt)
#pragma unroll
        for (int r = 0; r < 4; ++r) {
          int e = 4*lg + r;
          int ox = 2*(px0 + e) + bp_;
          int lx = ox - DX0;
          float v = fmaxf(acc[m][nt][r], 0.f);
          if ((unsigned)oy >= 256u || (unsigned)ox >= 256u) v = 0.f;
          int oc = nt*16 + lc;
          d2s[((ly*4 + (oc >> 3))*32 + lx)*8 + (oc & 7)] = f2b(v);
        }
    }
  }
  __syncthreads();
  for (int yy = w; yy < 14; yy += 4) {
    int gy = DY0 + 1 + yy;
#pragma unroll
    for (int xf = 0; xf < 2; ++xf) {
      float bv = (lc < 3) ? db3[lc] : 0.f;
      f32x4 acc = {bv, bv, bv, bv};
#pragma unroll
      for (int t = 0; t < 9; ++t) {
        int kh = t / 3, kw = t % 3;
        int lx = xf*16 + lc + kw; if (lx > 31) lx = 31;
        bf16x8 av = ld8(d2s + (((yy + kh)*4 + lg)*32 + lx)*8);
        bf16x8 bvv = ld8(b3l + t*512 + l*8);
        acc = MFMA(av, bvv, acc);
      }
      if (lc < 3 && (unsigned)gy < 256u) {
#pragma unroll
        for (int r = 0; r < 4; ++r) {
          int e = 4*lg + r;
          int xi = xf*16 + e;
          int gx = DX0 + 1 + xi;
          if (xi < 30 && (unsigned)gx < 256u)
            out[((size_t)(img*3 + lc)*256 + gy)*256 + gx] = 1.f / (1.f + expf(-acc[r]));
        }
      }
    }
  }
}

extern "C" void kernel_launch(void* const* d_in, const int* in_sizes, int n_in,
                              void* d_out, int out_size, void* d_ws, size_t ws_size,
                              hipStream_t stream) {
  const float* x   = (const float*)d_in[0];
  const float* ew1 = (const float*)d_in[1];
  const float* eb1 = (const float*)d_in[2];
  const float* ew2 = (const float*)d_in[3];
  const float* eb2 = (const float*)d_in[4];
  const float* ew3 = (const float*)d_in[5];
  const float* eb3 = (const float*)d_in[6];
  const float* cb  = (const float*)d_in[7];
  const float* dw1 = (const float*)d_in[8];
  const float* db1 = (const float*)d_in[9];
  const float* dw2 = (const float*)d_in[10];
  const float* db2 = (const float*)d_in[11];
  const float* dw3 = (const float*)d_in[12];
  const float* db3 = (const float*)d_in[13];
  float* out = (float*)d_out;

  // ws: h1/q [0,32M); d1 [16M,80M); h2 [32M,48M); z [48M,64M); weights @80M.
  char* ws = (char*)d_ws;
  const size_t MB = 1048576;
  u16* h1 = (u16*)ws;
  u16* q  = (u16*)ws;
  u16* d1 = (u16*)(ws + 16*MB);
  u16* h2 = (u16*)(ws + 32*MB);
  u16* z  = (u16*)(ws + 48*MB);
  char* wp = ws + 80*MB;
  float* W1   = (float*)wp;  wp += 6144;
  u16*  Bp2   = (u16*)wp;    wp += 65536;
  u16*  Bp3   = (u16*)wp;    wp += 73728;
  u16*  BpT1  = (u16*)wp;    wp += 131072;
  u16*  BpT2  = (u16*)wp;    wp += 65536;
  u16*  Bpd3  = (u16*)wp;    wp += 9216;
  u16*  Bpvq  = (u16*)wp;    wp += 65536;
  float* cnorm = (float*)wp; wp += 2048;
  float* loss = out + 6291456;

  prep_k<<<64, 256, 0, stream>>>(ew1, ew2, ew3, dw1, dw2, dw3, cb,
                                 W1, Bp2, Bp3, BpT1, BpT2, Bpd3, Bpvq, cnorm, loss);
  conv1_k<<<dim3(8, 16, 32), 256, 0, stream>>>(x, W1, eb1, h1);
  conv2_k<<<dim3(4, 8, 32), 256, 0, stream>>>(h1, Bp2, eb2, h2);
  conv3e_k<<<dim3(4, 8, 32), 256, 0, stream>>>(h2, Bp3, eb3, z);
  vqm_k<<<256, 256, 0, stream>>>(z, Bpvq, cnorm, cb, q, loss);
  convt1_k<<<dim3(4, 16, 32), 256, 0, stream>>>(q, BpT1, db1, d1);
  tail_k<<<dim3(9, 19, 32), 256, 0, stream>>>(d1, BpT2, db2, Bpd3, db3, out);
}

// Round 5
// 318.619 us; speedup vs baseline: 66.6298x; 1.0063x over previous
//
#include <hip/hip_runtime.h>

typedef unsigned short u16;
typedef unsigned int u32;
typedef __attribute__((ext_vector_type(8))) short bf16x8;
typedef __attribute__((ext_vector_type(4))) float f32x4;

#define MFMA(a, b, c) __builtin_amdgcn_mfma_f32_16x16x32_bf16(a, b, c, 0, 0, 0)

__device__ __forceinline__ float b2f(u32 lo16) {
  union { u32 i; float f; } v; v.i = lo16 << 16; return v.f;
}
__device__ __forceinline__ u16 f2b(float f) {  // RNE (encoder path)
  union { float f; u32 i; } v; v.f = f;
  return (u16)((v.i + 0x7fffu + ((v.i >> 16) & 1u)) >> 16);
}
__device__ __forceinline__ u16 f2bt(float f) {  // truncate (decoder path, 1 op)
  union { float f; u32 i; } v; v.f = f;
  return (u16)(v.i >> 16);
}
__device__ __forceinline__ bf16x8 ld8(const u16* p) { return *(const bf16x8*)p; }

// ---------------------------------------------------------------------------
// prep: pack weights into MFMA B-fragment order, cnorm, zero loss.
// B-frag: frag stored [64 lanes][8]; elem j of lane l = W[k=8*(l>>4)+j][n=l&15].
// ---------------------------------------------------------------------------
__global__ void prep_k(const float* __restrict__ ew1, const float* __restrict__ ew2,
                       const float* __restrict__ ew3, const float* __restrict__ dw1,
                       const float* __restrict__ dw2, const float* __restrict__ dw3,
                       const float* __restrict__ cb,
                       float* W1, u16* Bp2, u16* Bp3, u16* BpT1, u16* BpT2,
                       u16* Bpd3, u16* Bpvq, float* cnorm, float* loss) {
  int tid = blockIdx.x * blockDim.x + threadIdx.x;
  int nth = gridDim.x * blockDim.x;
  for (int i = tid; i < 1536; i += nth) {  // W1[3][4][4][32] f32 <- ew1[32][3][4][4]
    int oc = i & 31; int r = i >> 5; int kw = r & 3; r >>= 2; int kh = r & 3; int ic = r >> 2;
    W1[i] = ew1[((oc*3 + ic)*4 + kh)*4 + kw];
  }
  for (int i = tid; i < 32768; i += nth) {  // Bp2[t16][nt4][l][8] <- ew2[64][32][4][4]
    int j = i & 7, li = (i >> 3) & 63, nt = (i >> 9) & 3, t = i >> 11;
    int ic = 8*(li >> 4) + j, oc = 16*nt + (li & 15), kh = t >> 2, kw = t & 3;
    Bp2[i] = f2b(ew2[((oc*32 + ic)*4 + kh)*4 + kw]);
  }
  for (int i = tid; i < 36864; i += nth) {  // Bp3[t9][kc2][nt4][l][8] <- ew3[64][64][3][3]
    int j = i & 7, li = (i >> 3) & 63, nt = (i >> 9) & 3, kc = (i >> 11) & 1, t = i >> 12;
    int ic = 32*kc + 8*(li >> 4) + j, oc = 16*nt + (li & 15), kh = t / 3, kw = t % 3;
    Bp3[i] = f2b(ew3[((oc*64 + ic)*3 + kh)*3 + kw]);
  }
  for (int i = tid; i < 65536; i += nth) {  // BpT1[p4][t4][kc2][nt4][l][8] <- dw1[64][64][4][4]
    int j = i & 7, li = (i >> 3) & 63, nt = (i >> 9) & 3, kc = (i >> 11) & 1,
        t = (i >> 12) & 3, p = i >> 14;
    int a = p >> 1, b = p & 1;
    int ky = (1 - a) + 2*(t >> 1), kx = (1 - b) + 2*(t & 1);
    int ic = 32*kc + 8*(li >> 4) + j, oc = 16*nt + (li & 15);
    BpT1[i] = f2b(dw1[((ic*64 + oc)*4 + ky)*4 + kx]);
  }
  for (int i = tid; i < 32768; i += nth) {  // BpT2[p4][t4][kc2][nt2][l][8] <- dw2[64][32][4][4]
    int j = i & 7, li = (i >> 3) & 63, nt = (i >> 9) & 1, kc = (i >> 10) & 1,
        t = (i >> 11) & 3, p = i >> 13;
    int a = p >> 1, b = p & 1;
    int ky = (1 - a) + 2*(t >> 1), kx = (1 - b) + 2*(t & 1);
    int ic = 32*kc + 8*(li >> 4) + j, oc = 16*nt + (li & 15);
    BpT2[i] = f2b(dw2[((ic*32 + oc)*4 + ky)*4 + kx]);
  }
  for (int i = tid; i < 4608; i += nth) {  // Bpd3[t9][l][8] <- dw3[3][32][3][3], n pad 16
    int j = i & 7, li = (i >> 3) & 63, t = i >> 9;
    int n = li & 15, ic = 8*(li >> 4) + j, kh = t / 3, kw = t % 3;
    Bpd3[i] = (n < 3) ? f2b(dw3[((n*32 + ic)*3 + kh)*3 + kw]) : (u16)0;
  }
  for (int i = tid; i < 32768; i += nth) {  // Bpvq[kc2][nt32][l][8] <- cb[512][64]
    int j = i & 7, li = (i >> 3) & 63, nt = (i >> 9) & 31, kc = i >> 14;
    int d = 32*kc + 8*(li >> 4) + j, code = 16*nt + (li & 15);
    Bpvq[i] = f2b(cb[code*64 + d]);
  }
  for (int k = tid; k < 512; k += nth) {
    float s = 0.f;
    for (int d = 0; d < 64; ++d) { float c = cb[k*64 + d]; s += c*c; }
    cnorm[k] = s;
  }
  if (tid == 0) *loss = 0.f;
}

// ---------------------------------------------------------------------------
// conv1 (VALU): x f32 NCHW[32][3][256][256] -> h1 bf16 NHWC[32][128][128][32]
// ---------------------------------------------------------------------------
__global__ __launch_bounds__(256) void conv1_k(
    const float* __restrict__ x, const float* __restrict__ W1,
    const float* __restrict__ b1, u16* __restrict__ h1) {
  __shared__ float ins[3*18*36];
  int Tx = blockIdx.x, Ty = blockIdx.y, b = blockIdx.z;
  int tid = threadIdx.x;
  for (int i = tid; i < 3*18*36; i += 256) {
    int c = i % 36; int r = (i / 36) % 18; int ic = i / 648;
    int iy = 16*Ty - 1 + r, ix = 32*Tx - 2 + c;
    float v = 0.f;
    if ((unsigned)iy < 256u && (unsigned)ix < 256u)
      v = x[((size_t)(b*3 + ic)*256 + iy)*256 + ix];
    ins[i] = v;
  }
  __syncthreads();
  int posg = tid & 31, ocg = tid >> 5;
  int Y = posg >> 2, Xg = posg & 3;
  int oc0 = ocg * 4;
  float acc[4][4];
#pragma unroll
  for (int j = 0; j < 4; ++j) { float bv = b1[oc0 + j];
#pragma unroll
    for (int e = 0; e < 4; ++e) acc[j][e] = bv; }
  for (int ic = 0; ic < 3; ++ic)
#pragma unroll
    for (int kh = 0; kh < 4; ++kh) {
      const float* row = &ins[ic*648 + (2*Y + kh)*36 + 8*Xg];
      float win[12];
#pragma unroll
      for (int t = 0; t < 12; ++t) win[t] = row[t];
#pragma unroll
      for (int kw = 0; kw < 4; ++kw) {
        const float* wp = &W1[((ic*4 + kh)*4 + kw)*32 + oc0];
        float w0 = wp[0], w1 = wp[1], w2 = wp[2], w3 = wp[3];
#pragma unroll
        for (int e = 0; e < 4; ++e) {
          float v = win[2*e + kw + 1];
          acc[0][e] += w0*v; acc[1][e] += w1*v; acc[2][e] += w2*v; acc[3][e] += w3*v;
        }
      }
    }
  int oy = 8*Ty + Y;
  int oxb = 16*Tx + 4*Xg;
#pragma unroll
  for (int e = 0; e < 4; ++e) {
    u16* op = &h1[((size_t)(b*128 + oy)*128 + oxb + e)*32 + oc0];
#pragma unroll
    for (int j = 0; j < 4; ++j) op[j] = f2b(fmaxf(acc[j][e], 0.f));
  }
}

// ---------------------------------------------------------------------------
// conv2 (MFMA): h1 NHWC -> h2 bf16 NHWC[32][64][64][64], k4 s2 p1 relu.
// ---------------------------------------------------------------------------
__global__ __launch_bounds__(256) void conv2_k(
    const u16* __restrict__ h1, const u16* __restrict__ Bp2,
    const float* __restrict__ eb2, u16* __restrict__ h2) {
  __shared__ u16 lds[2448*8];  // [row18][c4][x34][8]
  int Tx = blockIdx.x, Ty = blockIdx.y, img = blockIdx.z;
  int tid = threadIdx.x;
  for (int i = tid; i < 2448; i += 256) {
    int c = i & 3; int x = (i >> 2) % 34; int row = (i >> 2) / 34;
    int iy = 16*Ty - 1 + row, ix = 32*Tx - 1 + x;
    f32x4 v = {0,0,0,0};
    if ((unsigned)iy < 128u && (unsigned)ix < 128u)
      v = *(const f32x4*)(h1 + (((size_t)(img*128 + iy)*128 + ix)*32 + c*8));
    *(f32x4*)(lds + ((row*4 + c)*34 + x)*8) = v;
  }
  __syncthreads();
  int w = tid >> 6, l = tid & 63, lg = l >> 4, lc = l & 15;
  f32x4 acc[2][4];
#pragma unroll
  for (int nt = 0; nt < 4; ++nt) {
    float bv = eb2[nt*16 + lc];
    acc[0][nt] = (f32x4){bv,bv,bv,bv}; acc[1][nt] = (f32x4){bv,bv,bv,bv};
  }
#pragma unroll
  for (int t = 0; t < 16; ++t) {
    int kh = t >> 2, kw = t & 3;
    bf16x8 a0 = ld8(lds + (((2*w + kh)*4 + lg)*34 + 2*lc + kw)*8);
    bf16x8 a1 = ld8(lds + (((2*(w+4) + kh)*4 + lg)*34 + 2*lc + kw)*8);
    const u16* bp = Bp2 + t*2048 + l*8;
    bf16x8 b0 = ld8(bp), b1 = ld8(bp + 512), b2v = ld8(bp + 1024), b3v = ld8(bp + 1536);
    acc[0][0] = MFMA(a0, b0, acc[0][0]); acc[0][1] = MFMA(a0, b1, acc[0][1]);
    acc[0][2] = MFMA(a0, b2v, acc[0][2]); acc[0][3] = MFMA(a0, b3v, acc[0][3]);
    acc[1][0] = MFMA(a1, b0, acc[1][0]); acc[1][1] = MFMA(a1, b1, acc[1][1]);
    acc[1][2] = MFMA(a1, b2v, acc[1][2]); acc[1][3] = MFMA(a1, b3v, acc[1][3]);
  }
#pragma unroll
  for (int m = 0; m < 2; ++m) {
    int oy = 8*Ty + w + m*4;
#pragma unroll
    for (int nt = 0; nt < 4; ++nt)
#pragma unroll
      for (int r = 0; r < 4; ++r) {
        int e = 4*lg + r;
        h2[((size_t)(img*64 + oy)*64 + 16*Tx + e)*64 + nt*16 + lc] =
            f2b(fmaxf(acc[m][nt][r], 0.f));
      }
  }
}

// ---------------------------------------------------------------------------
// conv3 enc (MFMA): h2 NHWC -> z bf16 NHWC[32][64][64][64], k3 s1 p1.
// ---------------------------------------------------------------------------
__global__ __launch_bounds__(256) void conv3e_k(
    const u16* __restrict__ h2, const u16* __restrict__ Bp3,
    const float* __restrict__ eb3, u16* __restrict__ z) {
  __shared__ u16 lds[1440*8];  // [row10][c8][x18][8]
  int Tx = blockIdx.x, Ty = blockIdx.y, img = blockIdx.z;
  int tid = threadIdx.x;
  for (int i = tid; i < 1440; i += 256) {
    int c = i & 7; int x = (i >> 3) % 18; int row = (i >> 3) / 18;
    int iy = 8*Ty - 1 + row, ix = 16*Tx - 1 + x;
    f32x4 v = {0,0,0,0};
    if ((unsigned)iy < 64u && (unsigned)ix < 64u)
      v = *(const f32x4*)(h2 + (((size_t)(img*64 + iy)*64 + ix)*64 + c*8));
    *(f32x4*)(lds + ((row*8 + c)*18 + x)*8) = v;
  }
  __syncthreads();
  int w = tid >> 6, l = tid & 63, lg = l >> 4, lc = l & 15;
  f32x4 acc[2][4];
#pragma unroll
  for (int nt = 0; nt < 4; ++nt) {
    float bv = eb3[nt*16 + lc];
    acc[0][nt] = (f32x4){bv,bv,bv,bv}; acc[1][nt] = (f32x4){bv,bv,bv,bv};
  }
#pragma unroll
  for (int t = 0; t < 9; ++t) {
    int kh = t / 3, kw = t % 3;
#pragma unroll
    for (int kc = 0; kc < 2; ++kc) {
      bf16x8 a0 = ld8(lds + (((w + kh)*8 + kc*4 + lg)*18 + lc + kw)*8);
      bf16x8 a1 = ld8(lds + (((w + 4 + kh)*8 + kc*4 + lg)*18 + lc + kw)*8);
      const u16* bp = Bp3 + (t*2 + kc)*2048 + l*8;
      bf16x8 b0 = ld8(bp), b1 = ld8(bp + 512), b2v = ld8(bp + 1024), b3v = ld8(bp + 1536);
      acc[0][0] = MFMA(a0, b0, acc[0][0]); acc[0][1] = MFMA(a0, b1, acc[0][1]);
      acc[0][2] = MFMA(a0, b2v, acc[0][2]); acc[0][3] = MFMA(a0, b3v, acc[0][3]);
      acc[1][0] = MFMA(a1, b0, acc[1][0]); acc[1][1] = MFMA(a1, b1, acc[1][1]);
      acc[1][2] = MFMA(a1, b2v, acc[1][2]); acc[1][3] = MFMA(a1, b3v, acc[1][3]);
    }
  }
#pragma unroll
  for (int m = 0; m < 2; ++m) {
    int oy = 8*Ty + w + m*4;
#pragma unroll
    for (int nt = 0; nt < 4; ++nt)
#pragma unroll
      for (int r = 0; r < 4; ++r) {
        int e = 4*lg + r;
        z[((size_t)(img*64 + oy)*64 + 16*Tx + e)*64 + nt*16 + lc] = f2b(acc[m][nt][r]);
      }
  }
}

// ---------------------------------------------------------------------------
// VQ (MFMA): z bf16 NHWC -> q bf16 NHWC + loss. M=131072, N=512, K=64.
// ---------------------------------------------------------------------------
__global__ __launch_bounds__(256) void vqm_k(
    const u16* __restrict__ z, const u16* __restrict__ Bpvq,
    const float* __restrict__ cnorm, const float* __restrict__ cbf,
    u16* __restrict__ q, float* __restrict__ loss) {
  __shared__ u16 cbl[32768];
  __shared__ float cnl[512];
  __shared__ int idxl[64];
  __shared__ float red[256];
  int tid = threadIdx.x;
  for (int i = tid; i < 4096; i += 256)
    *(f32x4*)(cbl + i*8) = *(const f32x4*)(Bpvq + i*8);
  for (int i = tid; i < 512; i += 256) cnl[i] = cnorm[i];
  __syncthreads();
  int w = tid >> 6, l = tid & 63, lg = l >> 4, lc = l & 15;
  int wglobal = blockIdx.x*4 + w;
  float lsum = 0.f;
  for (int it = 0; it < 8; ++it) {
    int mf = wglobal + it*1024;
    size_t P = (size_t)mf * 16;
    bf16x8 a0 = ld8(z + (P + lc)*64 + lg*8);
    bf16x8 a1 = ld8(z + (P + lc)*64 + 32 + lg*8);
    float best[4] = {1e30f, 1e30f, 1e30f, 1e30f};
    int bidx[4] = {0, 0, 0, 0};
    for (int nt = 0; nt < 32; ++nt) {
      f32x4 acc = {0,0,0,0};
      acc = MFMA(a0, ld8(cbl + (nt*64 + l)*8), acc);
      acc = MFMA(a1, ld8(cbl + ((32 + nt)*64 + l)*8), acc);
      float cn = cnl[nt*16 + lc];
      int code = nt*16 + lc;
#pragma unroll
      for (int r = 0; r < 4; ++r) {
        float dist = cn - 2.f*acc[r];
        if (dist < best[r]) { best[r] = dist; bidx[r] = code; }
      }
    }
#pragma unroll
    for (int r = 0; r < 4; ++r) {
      float b = best[r]; int bi = bidx[r];
      for (int m = 1; m < 16; m <<= 1) {
        float ob = __shfl_xor(b, m);
        int oi = __shfl_xor(bi, m);
        if (ob < b || (ob == b && oi < bi)) { b = ob; bi = oi; }
      }
      if (lc == 0) idxl[w*16 + lg*4 + r] = bi;
    }
    int m = lc, ch0 = lg*16;
    int id = idxl[w*16 + m];
    const float* crow = cbf + (size_t)id*64 + ch0;
    const u16* zp = z + (P + m)*64 + ch0;
    u32* qp = (u32*)(q + (P + m)*64 + ch0);
#pragma unroll
    for (int c = 0; c < 16; c += 2) {
      float c0 = crow[c], c1 = crow[c+1];
      float d0 = c0 - b2f(zp[c]), d1 = c1 - b2f(zp[c+1]);
      lsum += d0*d0 + d1*d1;
      qp[c >> 1] = (u32)f2bt(c0) | ((u32)f2bt(c1) << 16);
    }
  }
  red[tid] = lsum;
  __syncthreads();
  for (int s = 128; s > 0; s >>= 1) {
    if (tid < s) red[tid] += red[tid + s];
    __syncthreads();
  }
  if (tid == 0) atomicAdd(loss, red[0] * (1.25f / 8388608.f));
}

// ---------------------------------------------------------------------------
// convT1 (MFMA, parity): q NHWC -> d1 bf16 NHWC[32][128][128][64], k4 s2 p1 relu.
// ---------------------------------------------------------------------------
__global__ __launch_bounds__(256) void convt1_k(
    const u16* __restrict__ q, const u16* __restrict__ BpT1,
    const float* __restrict__ db1, u16* __restrict__ d1) {
  __shared__ u16 lds[864*8];  // [row6][c8][x18][8]
  int Tx = blockIdx.x, Ty = blockIdx.y, img = blockIdx.z;
  int X0 = 16*Tx, P0 = 4*Ty;
  int tid = threadIdx.x;
  for (int i = tid; i < 864; i += 256) {
    int c = i & 7; int x = (i >> 3) % 18; int row = (i >> 3) / 18;
    int iy = P0 - 1 + row, ix = X0 - 1 + x;
    f32x4 v = {0,0,0,0};
    if ((unsigned)iy < 64u && (unsigned)ix < 64u)
      v = *(const f32x4*)(q + (((size_t)(img*64 + iy)*64 + ix)*64 + c*8));
    *(f32x4*)(lds + ((row*8 + c)*18 + x)*8) = v;
  }
  __syncthreads();
  int w = tid >> 6, l = tid & 63, lg = l >> 4, lc = l & 15;
  int a = w & 1, bp_ = w >> 1;
  f32x4 acc[4][4];
#pragma unroll
  for (int nt = 0; nt < 4; ++nt) {
    float bv = db1[nt*16 + lc];
#pragma unroll
    for (int m = 0; m < 4; ++m) acc[m][nt] = (f32x4){bv,bv,bv,bv};
  }
  const u16* bbase = BpT1 + (size_t)(a*2 + bp_)*16384;
#pragma unroll
  for (int t = 0; t < 4; ++t) {
    int kyi = t >> 1, kxi = t & 1;
#pragma unroll
    for (int kc = 0; kc < 2; ++kc) {
      const u16* bp = bbase + (t*2 + kc)*2048 + l*8;
      bf16x8 b0 = ld8(bp), b1 = ld8(bp + 512), b2v = ld8(bp + 1024), b3v = ld8(bp + 1536);
      int xg = lc + bp_ - kxi + 1;
#pragma unroll
      for (int m = 0; m < 4; ++m) {
        int rowg = m + a - kyi + 1;
        bf16x8 av = ld8(lds + ((rowg*8 + kc*4 + lg)*18 + xg)*8);
        acc[m][0] = MFMA(av, b0, acc[m][0]);
        acc[m][1] = MFMA(av, b1, acc[m][1]);
        acc[m][2] = MFMA(av, b2v, acc[m][2]);
        acc[m][3] = MFMA(av, b3v, acc[m][3]);
      }
    }
  }
#pragma unroll
  for (int m = 0; m < 4; ++m) {
    int oy = 2*(P0 + m) + a;
#pragma unroll
    for (int nt = 0; nt < 4; ++nt)
#pragma unroll
      for (int r = 0; r < 4; ++r) {
        int e = 4*lg + r;
        int ox = 2*(X0 + e) + bp_;
        d1[((size_t)(img*128 + oy)*128 + ox)*64 + nt*16 + lc] =
            f2bt(fmaxf(acc[m][nt][r], 0.f));
      }
  }
}

// ---------------------------------------------------------------------------
// tail (MFMA): d2 = relu(convT2(d1)) into swizzled LDS (16y x 32x d2 tile,
// parity waves), then out = sigmoid(conv3x3(d2)) on 14y x 30x interior.
// d2s octet index XOR-swizzled with (lx>>3)&3 to break 16-way write conflicts.
// LDS: d1s [9][8][17][8] 19.1KB + d2s 32KB = 51.1KB -> 3 blocks/CU.
// ---------------------------------------------------------------------------
__global__ __launch_bounds__(256) void tail_k(
    const u16* __restrict__ d1, const u16* __restrict__ BpT2,
    const float* __restrict__ db2, const u16* __restrict__ Bpd3,
    const float* __restrict__ db3, float* __restrict__ out) {
  __shared__ u16 lds[1224*8];   // d1 halo [row9][c8][x17][8]
  __shared__ u16 d2s[2048*8];   // [ly16][c4][lx32][8], octet idx ^ ((lx>>3)&3)
  int Tx = blockIdx.x, Ty = blockIdx.y, img = blockIdx.z;
  int DX0 = 30*Tx - 1, DY0 = 14*Ty - 1;          // both always odd
  int IY0 = (DY0 - 2) >> 1, IX0 = (DX0 - 2) >> 1;
  int tid = threadIdx.x;
  for (int i = tid; i < 1224; i += 256) {
    int x = i % 17; int rc = i / 17; int c = rc & 7; int row = rc >> 3;
    int iy = IY0 + 1 + row, ix = IX0 + 1 + x;
    f32x4 v = {0,0,0,0};
    if ((unsigned)iy < 128u && (unsigned)ix < 128u)
      v = *(const f32x4*)(d1 + (((size_t)(img*128 + iy)*128 + ix)*64 + c*8));
    *(f32x4*)(lds + ((row*8 + c)*17 + x)*8) = v;
  }
  __syncthreads();
  int w = tid >> 6, l = tid & 63, lg = l >> 4, lc = l & 15;
  {
    int a = w & 1, bp_ = w >> 1;
    int py0 = (DY0 + ((DY0 ^ a) & 1)) >> 1;
    int px0 = (DX0 + ((DX0 ^ bp_) & 1)) >> 1;
    f32x4 acc[8][2];
#pragma unroll
    for (int nt = 0; nt < 2; ++nt) {
      float bv = db2[nt*16 + lc];
#pragma unroll
      for (int m = 0; m < 8; ++m) acc[m][nt] = (f32x4){bv,bv,bv,bv};
    }
    const u16* bbase = BpT2 + (size_t)(a*2 + bp_)*8192;
#pragma unroll
    for (int t = 0; t < 4; ++t) {
      int kyi = t >> 1, kxi = t & 1;
#pragma unroll
      for (int kc = 0; kc < 2; ++kc) {
        const u16* bb = bbase + (t*2 + kc)*1024 + l*8;
        bf16x8 b0 = ld8(bb), b1 = ld8(bb + 512);
        int xg = px0 + lc + bp_ - kxi - IX0 - 1;     // in [0,17)
#pragma unroll
        for (int m = 0; m < 8; ++m) {
          int rowg = py0 + m + a - kyi - IY0 - 1;    // in [0,9)
          bf16x8 av = ld8(lds + ((rowg*8 + kc*4 + lg)*17 + xg)*8);
          acc[m][0] = MFMA(av, b0, acc[m][0]);
          acc[m][1] = MFMA(av, b1, acc[m][1]);
        }
      }
    }
#pragma unroll
    for (int m = 0; m < 8; ++m) {
      int py = py0 + m; int oy = 2*py + a;
      int ly = oy - DY0;
#pragma unroll
      for (int nt = 0; nt < 2; ++nt)
#pragma unroll
        for (int r = 0; r < 4; ++r) {
          int e = 4*lg + r;
          int ox = 2*(px0 + e) + bp_;
          int lx = ox - DX0;
          float v = fmaxf(acc[m][nt][r], 0.f);
          if ((unsigned)oy >= 256u || (unsigned)ox >= 256u) v = 0.f;
          int oc = nt*16 + lc;
          int oi = (((ly*4 + (oc >> 3))*32 + lx)) ^ ((lx >> 3) & 3);
          d2s[oi*8 + (oc & 7)] = f2bt(v);
        }
    }
  }
  __syncthreads();
  // hoist phase-2 weight fragments (L2-resident, shared by all blocks)
  bf16x8 bw[9];
#pragma unroll
  for (int t = 0; t < 9; ++t) bw[t] = ld8(Bpd3 + t*512 + l*8);
  float bv3 = (lc < 3) ? db3[lc] : 0.f;
  for (int yy = w; yy < 14; yy += 4) {
    int gy = DY0 + 1 + yy;
#pragma unroll
    for (int xf = 0; xf < 2; ++xf) {
      f32x4 acc = {bv3, bv3, bv3, bv3};
#pragma unroll
      for (int t = 0; t < 9; ++t) {
        int kh = t / 3, kw = t % 3;
        int lx = xf*16 + lc + kw; if (lx > 31) lx = 31;
        int oi = (((yy + kh)*4 + lg)*32 + lx) ^ ((lx >> 3) & 3);
        bf16x8 av = ld8(d2s + oi*8);
        acc = MFMA(av, bw[t], acc);
      }
      if (lc < 3 && (unsigned)gy < 256u) {
#pragma unroll
        for (int r = 0; r < 4; ++r) {
          int e = 4*lg + r;
          int xi = xf*16 + e;
          int gx = DX0 + 1 + xi;
          if (xi < 30 && (unsigned)gx < 256u)
            out[((size_t)(img*3 + lc)*256 + gy)*256 + gx] = 1.f / (1.f + expf(-acc[r]));
        }
      }
    }
  }
}

extern "C" void kernel_launch(void* const* d_in, const int* in_sizes, int n_in,
                              void* d_out, int out_size, void* d_ws, size_t ws_size,
                              hipStream_t stream) {
  const float* x   = (const float*)d_in[0];
  const float* ew1 = (const float*)d_in[1];
  const float* eb1 = (const float*)d_in[2];
  const float* ew2 = (const float*)d_in[3];
  const float* eb2 = (const float*)d_in[4];
  const float* ew3 = (const float*)d_in[5];
  const float* eb3 = (const float*)d_in[6];
  const float* cb  = (const float*)d_in[7];
  const float* dw1 = (const float*)d_in[8];
  const float* db1 = (const float*)d_in[9];
  const float* dw2 = (const float*)d_in[10];
  const float* db2 = (const float*)d_in[11];
  const float* dw3 = (const float*)d_in[12];
  const float* db3 = (const float*)d_in[13];
  float* out = (float*)d_out;

  // ws: h1/q [0,32M); d1 [16M,80M); h2 [32M,48M); z [48M,64M); weights @80M.
  char* ws = (char*)d_ws;
  const size_t MB = 1048576;
  u16* h1 = (u16*)ws;
  u16* q  = (u16*)ws;
  u16* d1 = (u16*)(ws + 16*MB);
  u16* h2 = (u16*)(ws + 32*MB);
  u16* z  = (u16*)(ws + 48*MB);
  char* wp = ws + 80*MB;
  float* W1   = (float*)wp;  wp += 6144;
  u16*  Bp2   = (u16*)wp;    wp += 65536;
  u16*  Bp3   = (u16*)wp;    wp += 73728;
  u16*  BpT1  = (u16*)wp;    wp += 131072;
  u16*  BpT2  = (u16*)wp;    wp += 65536;
  u16*  Bpd3  = (u16*)wp;    wp += 9216;
  u16*  Bpvq  = (u16*)wp;    wp += 65536;
  float* cnorm = (float*)wp; wp += 2048;
  float* loss = out + 6291456;

  prep_k<<<64, 256, 0, stream>>>(ew1, ew2, ew3, dw1, dw2, dw3, cb,
                                 W1, Bp2, Bp3, BpT1, BpT2, Bpd3, Bpvq, cnorm, loss);
  conv1_k<<<dim3(8, 16, 32), 256, 0, stream>>>(x, W1, eb1, h1);
  conv2_k<<<dim3(4, 8, 32), 256, 0, stream>>>(h1, Bp2, eb2, h2);
  conv3e_k<<<dim3(4, 8, 32), 256, 0, stream>>>(h2, Bp3, eb3, z);
  vqm_k<<<256, 256, 0, stream>>>(z, Bpvq, cnorm, cb, q, loss);
  convt1_k<<<dim3(4, 16, 32), 256, 0, stream>>>(q, BpT1, db1, d1);
  tail_k<<<dim3(9, 19, 32), 256, 0, stream>>>(d1, BpT2, db2, Bpd3, db3, out);
}

// Round 6
// 290.521 us; speedup vs baseline: 73.0739x; 1.0967x over previous
//
#include <hip/hip_runtime.h>

typedef unsigned short u16;
typedef unsigned int u32;
typedef __attribute__((ext_vector_type(8))) short bf16x8;
typedef __attribute__((ext_vector_type(4))) float f32x4;

#define MFMA(a, b, c) __builtin_amdgcn_mfma_f32_16x16x32_bf16(a, b, c, 0, 0, 0)

__device__ __forceinline__ float b2f(u32 lo16) {
  union { u32 i; float f; } v; v.i = lo16 << 16; return v.f;
}
__device__ __forceinline__ u16 f2b(float f) {  // RNE (encoder path)
  union { float f; u32 i; } v; v.f = f;
  return (u16)((v.i + 0x7fffu + ((v.i >> 16) & 1u)) >> 16);
}
__device__ __forceinline__ u16 f2bt(float f) {  // truncate (decoder path, 1 op)
  union { float f; u32 i; } v; v.f = f;
  return (u16)(v.i >> 16);
}
__device__ __forceinline__ bf16x8 ld8(const u16* p) { return *(const bf16x8*)p; }

// ---------------------------------------------------------------------------
// prep: pack weights into MFMA B-fragment order, cnorm, zero loss.
// B-frag: frag stored [64 lanes][8]; elem j of lane l = W[k=8*(l>>4)+j][n=l&15].
// ---------------------------------------------------------------------------
__global__ void prep_k(const float* __restrict__ ew1, const float* __restrict__ ew2,
                       const float* __restrict__ ew3, const float* __restrict__ dw1,
                       const float* __restrict__ dw2, const float* __restrict__ dw3,
                       const float* __restrict__ cb,
                       float* W1, u16* Bp2, u16* Bp3, u16* BpT1, u16* BpT2,
                       u16* Bpd3, u16* Bpvq, float* cnorm, float* loss) {
  int tid = blockIdx.x * blockDim.x + threadIdx.x;
  int nth = gridDim.x * blockDim.x;
  for (int i = tid; i < 1536; i += nth) {  // W1[3][4][4][32] f32 <- ew1[32][3][4][4]
    int oc = i & 31; int r = i >> 5; int kw = r & 3; r >>= 2; int kh = r & 3; int ic = r >> 2;
    W1[i] = ew1[((oc*3 + ic)*4 + kh)*4 + kw];
  }
  for (int i = tid; i < 32768; i += nth) {  // Bp2[t16][nt4][l][8] <- ew2[64][32][4][4]
    int j = i & 7, li = (i >> 3) & 63, nt = (i >> 9) & 3, t = i >> 11;
    int ic = 8*(li >> 4) + j, oc = 16*nt + (li & 15), kh = t >> 2, kw = t & 3;
    Bp2[i] = f2b(ew2[((oc*32 + ic)*4 + kh)*4 + kw]);
  }
  for (int i = tid; i < 36864; i += nth) {  // Bp3[t9][kc2][nt4][l][8] <- ew3[64][64][3][3]
    int j = i & 7, li = (i >> 3) & 63, nt = (i >> 9) & 3, kc = (i >> 11) & 1, t = i >> 12;
    int ic = 32*kc + 8*(li >> 4) + j, oc = 16*nt + (li & 15), kh = t / 3, kw = t % 3;
    Bp3[i] = f2b(ew3[((oc*64 + ic)*3 + kh)*3 + kw]);
  }
  for (int i = tid; i < 65536; i += nth) {  // BpT1[p4][t4][kc2][nt4][l][8] <- dw1[64][64][4][4]
    int j = i & 7, li = (i >> 3) & 63, nt = (i >> 9) & 3, kc = (i >> 11) & 1,
        t = (i >> 12) & 3, p = i >> 14;
    int a = p >> 1, b = p & 1;
    int ky = (1 - a) + 2*(t >> 1), kx = (1 - b) + 2*(t & 1);
    int ic = 32*kc + 8*(li >> 4) + j, oc = 16*nt + (li & 15);
    BpT1[i] = f2b(dw1[((ic*64 + oc)*4 + ky)*4 + kx]);
  }
  for (int i = tid; i < 32768; i += nth) {  // BpT2[p4][t4][kc2][nt2][l][8] <- dw2[64][32][4][4]
    int j = i & 7, li = (i >> 3) & 63, nt = (i >> 9) & 1, kc = (i >> 10) & 1,
        t = (i >> 11) & 3, p = i >> 13;
    int a = p >> 1, b = p & 1;
    int ky = (1 - a) + 2*(t >> 1), kx = (1 - b) + 2*(t & 1);
    int ic = 32*kc + 8*(li >> 4) + j, oc = 16*nt + (li & 15);
    BpT2[i] = f2b(dw2[((ic*32 + oc)*4 + ky)*4 + kx]);
  }
  for (int i = tid; i < 4608; i += nth) {  // Bpd3[t9][l][8] <- dw3[3][32][3][3], n pad 16
    int j = i & 7, li = (i >> 3) & 63, t = i >> 9;
    int n = li & 15, ic = 8*(li >> 4) + j, kh = t / 3, kw = t % 3;
    Bpd3[i] = (n < 3) ? f2b(dw3[((n*32 + ic)*3 + kh)*3 + kw]) : (u16)0;
  }
  for (int i = tid; i < 32768; i += nth) {  // Bpvq[kc2][nt32][l][8] <- cb[512][64]
    int j = i & 7, li = (i >> 3) & 63, nt = (i >> 9) & 31, kc = i >> 14;
    int d = 32*kc + 8*(li >> 4) + j, code = 16*nt + (li & 15);
    Bpvq[i] = f2b(cb[code*64 + d]);
  }
  for (int k = tid; k < 512; k += nth) {
    float s = 0.f;
    for (int d = 0; d < 64; ++d) { float c = cb[k*64 + d]; s += c*c; }
    cnorm[k] = s;
  }
  if (tid == 0) *loss = 0.f;
}

// ---------------------------------------------------------------------------
// conv1 (VALU): x f32 NCHW[32][3][256][256] -> h1 bf16 NHWC[32][128][128][32]
// ---------------------------------------------------------------------------
__global__ __launch_bounds__(256) void conv1_k(
    const float* __restrict__ x, const float* __restrict__ W1,
    const float* __restrict__ b1, u16* __restrict__ h1) {
  __shared__ float ins[3*18*36];
  int Tx = blockIdx.x, Ty = blockIdx.y, b = blockIdx.z;
  int tid = threadIdx.x;
  for (int i = tid; i < 3*18*36; i += 256) {
    int c = i % 36; int r = (i / 36) % 18; int ic = i / 648;
    int iy = 16*Ty - 1 + r, ix = 32*Tx - 2 + c;
    float v = 0.f;
    if ((unsigned)iy < 256u && (unsigned)ix < 256u)
      v = x[((size_t)(b*3 + ic)*256 + iy)*256 + ix];
    ins[i] = v;
  }
  __syncthreads();
  int posg = tid & 31, ocg = tid >> 5;
  int Y = posg >> 2, Xg = posg & 3;
  int oc0 = ocg * 4;
  float acc[4][4];
#pragma unroll
  for (int j = 0; j < 4; ++j) { float bv = b1[oc0 + j];
#pragma unroll
    for (int e = 0; e < 4; ++e) acc[j][e] = bv; }
  for (int ic = 0; ic < 3; ++ic)
#pragma unroll
    for (int kh = 0; kh < 4; ++kh) {
      const float* row = &ins[ic*648 + (2*Y + kh)*36 + 8*Xg];
      float win[12];
#pragma unroll
      for (int t = 0; t < 12; ++t) win[t] = row[t];
#pragma unroll
      for (int kw = 0; kw < 4; ++kw) {
        const float* wp = &W1[((ic*4 + kh)*4 + kw)*32 + oc0];
        float w0 = wp[0], w1 = wp[1], w2 = wp[2], w3 = wp[3];
#pragma unroll
        for (int e = 0; e < 4; ++e) {
          float v = win[2*e + kw + 1];
          acc[0][e] += w0*v; acc[1][e] += w1*v; acc[2][e] += w2*v; acc[3][e] += w3*v;
        }
      }
    }
  int oy = 8*Ty + Y;
  int oxb = 16*Tx + 4*Xg;
#pragma unroll
  for (int e = 0; e < 4; ++e) {
    u16* op = &h1[((size_t)(b*128 + oy)*128 + oxb + e)*32 + oc0];
#pragma unroll
    for (int j = 0; j < 4; ++j) op[j] = f2b(fmaxf(acc[j][e], 0.f));
  }
}

// ---------------------------------------------------------------------------
// conv2 (MFMA): h1 NHWC -> h2 bf16 NHWC[32][64][64][64], k4 s2 p1 relu.
// ---------------------------------------------------------------------------
__global__ __launch_bounds__(256) void conv2_k(
    const u16* __restrict__ h1, const u16* __restrict__ Bp2,
    const float* __restrict__ eb2, u16* __restrict__ h2) {
  __shared__ u16 lds[2448*8];  // [row18][c4][x34][8]
  int Tx = blockIdx.x, Ty = blockIdx.y, img = blockIdx.z;
  int tid = threadIdx.x;
  for (int i = tid; i < 2448; i += 256) {
    int c = i & 3; int x = (i >> 2) % 34; int row = (i >> 2) / 34;
    int iy = 16*Ty - 1 + row, ix = 32*Tx - 1 + x;
    f32x4 v = {0,0,0,0};
    if ((unsigned)iy < 128u && (unsigned)ix < 128u)
      v = *(const f32x4*)(h1 + (((size_t)(img*128 + iy)*128 + ix)*32 + c*8));
    *(f32x4*)(lds + ((row*4 + c)*34 + x)*8) = v;
  }
  __syncthreads();
  int w = tid >> 6, l = tid & 63, lg = l >> 4, lc = l & 15;
  f32x4 acc[2][4];
#pragma unroll
  for (int nt = 0; nt < 4; ++nt) {
    float bv = eb2[nt*16 + lc];
    acc[0][nt] = (f32x4){bv,bv,bv,bv}; acc[1][nt] = (f32x4){bv,bv,bv,bv};
  }
#pragma unroll
  for (int t = 0; t < 16; ++t) {
    int kh = t >> 2, kw = t & 3;
    bf16x8 a0 = ld8(lds + (((2*w + kh)*4 + lg)*34 + 2*lc + kw)*8);
    bf16x8 a1 = ld8(lds + (((2*(w+4) + kh)*4 + lg)*34 + 2*lc + kw)*8);
    const u16* bp = Bp2 + t*2048 + l*8;
    bf16x8 b0 = ld8(bp), b1 = ld8(bp + 512), b2v = ld8(bp + 1024), b3v = ld8(bp + 1536);
    acc[0][0] = MFMA(a0, b0, acc[0][0]); acc[0][1] = MFMA(a0, b1, acc[0][1]);
    acc[0][2] = MFMA(a0, b2v, acc[0][2]); acc[0][3] = MFMA(a0, b3v, acc[0][3]);
    acc[1][0] = MFMA(a1, b0, acc[1][0]); acc[1][1] = MFMA(a1, b1, acc[1][1]);
    acc[1][2] = MFMA(a1, b2v, acc[1][2]); acc[1][3] = MFMA(a1, b3v, acc[1][3]);
  }
#pragma unroll
  for (int m = 0; m < 2; ++m) {
    int oy = 8*Ty + w + m*4;
#pragma unroll
    for (int nt = 0; nt < 4; ++nt)
#pragma unroll
      for (int r = 0; r < 4; ++r) {
        int e = 4*lg + r;
        h2[((size_t)(img*64 + oy)*64 + 16*Tx + e)*64 + nt*16 + lc] =
            f2b(fmaxf(acc[m][nt][r], 0.f));
      }
  }
}

// ---------------------------------------------------------------------------
// conv3 enc (MFMA): h2 NHWC -> z bf16 NHWC[32][64][64][64], k3 s1 p1.
// ---------------------------------------------------------------------------
__global__ __launch_bounds__(256) void conv3e_k(
    const u16* __restrict__ h2, const u16* __restrict__ Bp3,
    const float* __restrict__ eb3, u16* __restrict__ z) {
  __shared__ u16 lds[1440*8];  // [row10][c8][x18][8]
  int Tx = blockIdx.x, Ty = blockIdx.y, img = blockIdx.z;
  int tid = threadIdx.x;
  for (int i = tid; i < 1440; i += 256) {
    int c = i & 7; int x = (i >> 3) % 18; int row = (i >> 3) / 18;
    int iy = 8*Ty - 1 + row, ix = 16*Tx - 1 + x;
    f32x4 v = {0,0,0,0};
    if ((unsigned)iy < 64u && (unsigned)ix < 64u)
      v = *(const f32x4*)(h2 + (((size_t)(img*64 + iy)*64 + ix)*64 + c*8));
    *(f32x4*)(lds + ((row*8 + c)*18 + x)*8) = v;
  }
  __syncthreads();
  int w = tid >> 6, l = tid & 63, lg = l >> 4, lc = l & 15;
  f32x4 acc[2][4];
#pragma unroll
  for (int nt = 0; nt < 4; ++nt) {
    float bv = eb3[nt*16 + lc];
    acc[0][nt] = (f32x4){bv,bv,bv,bv}; acc[1][nt] = (f32x4){bv,bv,bv,bv};
  }
#pragma unroll
  for (int t = 0; t < 9; ++t) {
    int kh = t / 3, kw = t % 3;
#pragma unroll
    for (int kc = 0; kc < 2; ++kc) {
      bf16x8 a0 = ld8(lds + (((w + kh)*8 + kc*4 + lg)*18 + lc + kw)*8);
      bf16x8 a1 = ld8(lds + (((w + 4 + kh)*8 + kc*4 + lg)*18 + lc + kw)*8);
      const u16* bp = Bp3 + (t*2 + kc)*2048 + l*8;
      bf16x8 b0 = ld8(bp), b1 = ld8(bp + 512), b2v = ld8(bp + 1024), b3v = ld8(bp + 1536);
      acc[0][0] = MFMA(a0, b0, acc[0][0]); acc[0][1] = MFMA(a0, b1, acc[0][1]);
      acc[0][2] = MFMA(a0, b2v, acc[0][2]); acc[0][3] = MFMA(a0, b3v, acc[0][3]);
      acc[1][0] = MFMA(a1, b0, acc[1][0]); acc[1][1] = MFMA(a1, b1, acc[1][1]);
      acc[1][2] = MFMA(a1, b2v, acc[1][2]); acc[1][3] = MFMA(a1, b3v, acc[1][3]);
    }
  }
#pragma unroll
  for (int m = 0; m < 2; ++m) {
    int oy = 8*Ty + w + m*4;
#pragma unroll
    for (int nt = 0; nt < 4; ++nt)
#pragma unroll
      for (int r = 0; r < 4; ++r) {
        int e = 4*lg + r;
        z[((size_t)(img*64 + oy)*64 + 16*Tx + e)*64 + nt*16 + lc] = f2b(acc[m][nt][r]);
      }
  }
}

// ---------------------------------------------------------------------------
// VQ (MFMA): z bf16 NHWC -> q bf16 NHWC + loss. M=131072, N=512, K=64.
// ---------------------------------------------------------------------------
__global__ __launch_bounds__(256) void vqm_k(
    const u16* __restrict__ z, const u16* __restrict__ Bpvq,
    const float* __restrict__ cnorm, const float* __restrict__ cbf,
    u16* __restrict__ q, float* __restrict__ loss) {
  __shared__ u16 cbl[32768];
  __shared__ float cnl[512];
  __shared__ int idxl[64];
  __shared__ float red[256];
  int tid = threadIdx.x;
  for (int i = tid; i < 4096; i += 256)
    *(f32x4*)(cbl + i*8) = *(const f32x4*)(Bpvq + i*8);
  for (int i = tid; i < 512; i += 256) cnl[i] = cnorm[i];
  __syncthreads();
  int w = tid >> 6, l = tid & 63, lg = l >> 4, lc = l & 15;
  int wglobal = blockIdx.x*4 + w;
  float lsum = 0.f;
  for (int it = 0; it < 8; ++it) {
    int mf = wglobal + it*1024;
    size_t P = (size_t)mf * 16;
    bf16x8 a0 = ld8(z + (P + lc)*64 + lg*8);
    bf16x8 a1 = ld8(z + (P + lc)*64 + 32 + lg*8);
    float best[4] = {1e30f, 1e30f, 1e30f, 1e30f};
    int bidx[4] = {0, 0, 0, 0};
    for (int nt = 0; nt < 32; ++nt) {
      f32x4 acc = {0,0,0,0};
      acc = MFMA(a0, ld8(cbl + (nt*64 + l)*8), acc);
      acc = MFMA(a1, ld8(cbl + ((32 + nt)*64 + l)*8), acc);
      float cn = cnl[nt*16 + lc];
      int code = nt*16 + lc;
#pragma unroll
      for (int r = 0; r < 4; ++r) {
        float dist = cn - 2.f*acc[r];
        if (dist < best[r]) { best[r] = dist; bidx[r] = code; }
      }
    }
#pragma unroll
    for (int r = 0; r < 4; ++r) {
      float b = best[r]; int bi = bidx[r];
      for (int m = 1; m < 16; m <<= 1) {
        float ob = __shfl_xor(b, m);
        int oi = __shfl_xor(bi, m);
        if (ob < b || (ob == b && oi < bi)) { b = ob; bi = oi; }
      }
      if (lc == 0) idxl[w*16 + lg*4 + r] = bi;
    }
    int m = lc, ch0 = lg*16;
    int id = idxl[w*16 + m];
    const float* crow = cbf + (size_t)id*64 + ch0;
    const u16* zp = z + (P + m)*64 + ch0;
    u32* qp = (u32*)(q + (P + m)*64 + ch0);
#pragma unroll
    for (int c = 0; c < 16; c += 2) {
      float c0 = crow[c], c1 = crow[c+1];
      float d0 = c0 - b2f(zp[c]), d1 = c1 - b2f(zp[c+1]);
      lsum += d0*d0 + d1*d1;
      qp[c >> 1] = (u32)f2bt(c0) | ((u32)f2bt(c1) << 16);
    }
  }
  red[tid] = lsum;
  __syncthreads();
  for (int s = 128; s > 0; s >>= 1) {
    if (tid < s) red[tid] += red[tid + s];
    __syncthreads();
  }
  if (tid == 0) atomicAdd(loss, red[0] * (1.25f / 8388608.f));
}

// ---------------------------------------------------------------------------
// convT1 (MFMA, parity): q NHWC -> d1 bf16 NHWC[32][128][128][64], k4 s2 p1 relu.
// ---------------------------------------------------------------------------
__global__ __launch_bounds__(256) void convt1_k(
    const u16* __restrict__ q, const u16* __restrict__ BpT1,
    const float* __restrict__ db1, u16* __restrict__ d1) {
  __shared__ u16 lds[864*8];  // [row6][c8][x18][8]
  int Tx = blockIdx.x, Ty = blockIdx.y, img = blockIdx.z;
  int X0 = 16*Tx, P0 = 4*Ty;
  int tid = threadIdx.x;
  for (int i = tid; i < 864; i += 256) {
    int c = i & 7; int x = (i >> 3) % 18; int row = (i >> 3) / 18;
    int iy = P0 - 1 + row, ix = X0 - 1 + x;
    f32x4 v = {0,0,0,0};
    if ((unsigned)iy < 64u && (unsigned)ix < 64u)
      v = *(const f32x4*)(q + (((size_t)(img*64 + iy)*64 + ix)*64 + c*8));
    *(f32x4*)(lds + ((row*8 + c)*18 + x)*8) = v;
  }
  __syncthreads();
  int w = tid >> 6, l = tid & 63, lg = l >> 4, lc = l & 15;
  int a = w & 1, bp_ = w >> 1;
  f32x4 acc[4][4];
#pragma unroll
  for (int nt = 0; nt < 4; ++nt) {
    float bv = db1[nt*16 + lc];
#pragma unroll
    for (int m = 0; m < 4; ++m) acc[m][nt] = (f32x4){bv,bv,bv,bv};
  }
  const u16* bbase = BpT1 + (size_t)(a*2 + bp_)*16384;
#pragma unroll
  for (int t = 0; t < 4; ++t) {
    int kyi = t >> 1, kxi = t & 1;
#pragma unroll
    for (int kc = 0; kc < 2; ++kc) {
      const u16* bp = bbase + (t*2 + kc)*2048 + l*8;
      bf16x8 b0 = ld8(bp), b1 = ld8(bp + 512), b2v = ld8(bp + 1024), b3v = ld8(bp + 1536);
      int xg = lc + bp_ - kxi + 1;
#pragma unroll
      for (int m = 0; m < 4; ++m) {
        int rowg = m + a - kyi + 1;
        bf16x8 av = ld8(lds + ((rowg*8 + kc*4 + lg)*18 + xg)*8);
        acc[m][0] = MFMA(av, b0, acc[m][0]);
        acc[m][1] = MFMA(av, b1, acc[m][1]);
        acc[m][2] = MFMA(av, b2v, acc[m][2]);
        acc[m][3] = MFMA(av, b3v, acc[m][3]);
      }
    }
  }
#pragma unroll
  for (int m = 0; m < 4; ++m) {
    int oy = 2*(P0 + m) + a;
#pragma unroll
    for (int nt = 0; nt < 4; ++nt)
#pragma unroll
      for (int r = 0; r < 4; ++r) {
        int e = 4*lg + r;
        int ox = 2*(X0 + e) + bp_;
        d1[((size_t)(img*128 + oy)*128 + ox)*64 + nt*16 + lc] =
            f2bt(fmaxf(acc[m][nt][r], 0.f));
      }
  }
}

// ---------------------------------------------------------------------------
// tail (MFMA): small-tile fused convT2+relu+conv3+sigmoid.
// Block: 8-row x 32-col d2 tile (quadrant LDS), 6x30 output interior.
// d2q[quad4][m4][e16][oc32], oc slot ^ ((e&4)<<2). LDS 27.3KB -> 5-6 blocks/CU.
// ---------------------------------------------------------------------------
__global__ __launch_bounds__(256) void tail_k(
    const u16* __restrict__ d1, const u16* __restrict__ BpT2,
    const float* __restrict__ db2, const u16* __restrict__ Bpd3,
    const float* __restrict__ db3, float* __restrict__ out) {
  __shared__ u16 d1s[680*8];   // [row5][c8][x17][8]
  __shared__ u16 d2q[8192];    // [quad4][m4][e16][oc32]
  int Tx = blockIdx.x, Ty = blockIdx.y, img = blockIdx.z;
  int DX0 = 30*Tx - 1, DY0 = 6*Ty - 1;   // both odd
  int IYB = 3*Ty, IXB = 15*Tx;           // (DY0+1)/2, (DX0+1)/2
  int tid = threadIdx.x;
  // stage d1 rows IYB-1..IYB+3, cols IXB-1..IXB+15
  for (int i = tid; i < 680; i += 256) {
    int x = i % 17; int rc = i / 17; int c = rc & 7; int row = rc >> 3;
    int iy = IYB - 1 + row, ix = IXB - 1 + x;
    f32x4 v = {0,0,0,0};
    if ((unsigned)iy < 128u && (unsigned)ix < 128u)
      v = *(const f32x4*)(d1 + (((size_t)(img*128 + iy)*128 + ix)*64 + c*8));
    *(f32x4*)(d1s + ((row*8 + c)*17 + x)*8) = v;
  }
  __syncthreads();
  int w = tid >> 6, l = tid & 63, lg = l >> 4, lc = l & 15;
  {
    int a = w & 1, b = w >> 1;
    f32x4 acc[4][2];
#pragma unroll
    for (int nt = 0; nt < 2; ++nt) {
      float bv = db2[nt*16 + lc];
#pragma unroll
      for (int m = 0; m < 4; ++m) acc[m][nt] = (f32x4){bv,bv,bv,bv};
    }
    const u16* bbase = BpT2 + (size_t)(a*2 + b)*8192;
#pragma unroll
    for (int kxi = 0; kxi < 2; ++kxi) {
      int xg = lc - kxi + 1;
#pragma unroll
      for (int kc = 0; kc < 2; ++kc) {
        bf16x8 av[5];
#pragma unroll
        for (int rr = 0; rr < 5; ++rr)
          av[rr] = ld8(d1s + ((rr*8 + kc*4 + lg)*17 + xg)*8);
#pragma unroll
        for (int kyi = 0; kyi < 2; ++kyi) {
          int t = kyi*2 + kxi;
          const u16* bb = bbase + (t*2 + kc)*1024 + l*8;
          bf16x8 b0 = ld8(bb), b1 = ld8(bb + 512);
#pragma unroll
          for (int m = 0; m < 4; ++m) {
            acc[m][0] = MFMA(av[m + 1 - kyi], b0, acc[m][0]);
            acc[m][1] = MFMA(av[m + 1 - kyi], b1, acc[m][1]);
          }
        }
      }
    }
    // epilogue: write into quadrant LDS, masks hoisted
    int oyb = DY0 + (1 - a);            // + 2m
    int oxb = DX0 + (1 - b) + 8*lg;     // + 2r
    bool cm[4];
#pragma unroll
    for (int r = 0; r < 4; ++r) cm[r] = (unsigned)(oxb + 2*r) < 256u;
    int base = (a*2 + b)*2048 + lg*128 + lc;
    int ntk = (lg & 1);
#pragma unroll
    for (int m = 0; m < 4; ++m) {
      bool rm = (unsigned)(oyb + 2*m) < 256u;
#pragma unroll
      for (int nt = 0; nt < 2; ++nt) {
        int wb = base + m*512 + ((nt ^ ntk) << 4);
#pragma unroll
        for (int r = 0; r < 4; ++r) {
          float v = (rm && cm[r]) ? fmaxf(acc[m][nt][r], 0.f) : 0.f;
          d2q[wb + r*32] = f2bt(v);
        }
      }
    }
  }
  __syncthreads();
  // phase 2: conv3x3 (32ic -> 3oc padded 16) + sigmoid on 6x30 interior
  bf16x8 bw[9];
#pragma unroll
  for (int t = 0; t < 9; ++t) bw[t] = ld8(Bpd3 + t*512 + l*8);
  float bv3 = (lc < 3) ? db3[lc] : 0.f;
#pragma unroll
  for (int i = 0; i < 3; ++i) {
    int u = w + 4*i;                 // 12 units, 3 per wave
    int yy = u >> 1, xf = u & 1;
    int gy = DY0 + 1 + yy;
    f32x4 acc = {bv3, bv3, bv3, bv3};
#pragma unroll
    for (int t = 0; t < 9; ++t) {
      int kh = t / 3, kw = t % 3;
      int ly = yy + kh;                       // [0,8)
      int lx = xf*16 + lc + kw;               // [0,34) -> clamp
      if (lx > 31) lx = 31;
      int quad = (1 - (ly & 1))*2 + (1 - (lx & 1));
      int ridx = quad*2048 + (ly >> 1)*512 + (lx >> 1)*32 + ((lg*8) ^ ((lx & 8)*2));
      acc = MFMA(ld8(d2q + ridx), bw[t], acc);
    }
    if (lc < 3 && (unsigned)gy < 256u) {
#pragma unroll
      for (int r = 0; r < 4; ++r) {
        int xi = xf*16 + 4*lg + r;
        int gx = DX0 + 1 + xi;
        if (xi < 30 && (unsigned)gx < 256u)
          out[((size_t)(img*3 + lc)*256 + gy)*256 + gx] = 1.f / (1.f + expf(-acc[r]));
      }
    }
  }
}

extern "C" void kernel_launch(void* const* d_in, const int* in_sizes, int n_in,
                              void* d_out, int out_size, void* d_ws, size_t ws_size,
                              hipStream_t stream) {
  const float* x   = (const float*)d_in[0];
  const float* ew1 = (const float*)d_in[1];
  const float* eb1 = (const float*)d_in[2];
  const float* ew2 = (const float*)d_in[3];
  const float* eb2 = (const float*)d_in[4];
  const float* ew3 = (const float*)d_in[5];
  const float* eb3 = (const float*)d_in[6];
  const float* cb  = (const float*)d_in[7];
  const float* dw1 = (const float*)d_in[8];
  const float* db1 = (const float*)d_in[9];
  const float* dw2 = (const float*)d_in[10];
  const float* db2 = (const float*)d_in[11];
  const float* dw3 = (const float*)d_in[12];
  const float* db3 = (const float*)d_in[13];
  float* out = (float*)d_out;

  // ws: h1/q [0,32M); d1 [16M,80M); h2 [32M,48M); z [48M,64M); weights @80M.
  char* ws = (char*)d_ws;
  const size_t MB = 1048576;
  u16* h1 = (u16*)ws;
  u16* q  = (u16*)ws;
  u16* d1 = (u16*)(ws + 16*MB);
  u16* h2 = (u16*)(ws + 32*MB);
  u16* z  = (u16*)(ws + 48*MB);
  char* wp = ws + 80*MB;
  float* W1   = (float*)wp;  wp += 6144;
  u16*  Bp2   = (u16*)wp;    wp += 65536;
  u16*  Bp3   = (u16*)wp;    wp += 73728;
  u16*  BpT1  = (u16*)wp;    wp += 131072;
  u16*  BpT2  = (u16*)wp;    wp += 65536;
  u16*  Bpd3  = (u16*)wp;    wp += 9216;
  u16*  Bpvq  = (u16*)wp;    wp += 65536;
  float* cnorm = (float*)wp; wp += 2048;
  float* loss = out + 6291456;

  prep_k<<<64, 256, 0, stream>>>(ew1, ew2, ew3, dw1, dw2, dw3, cb,
                                 W1, Bp2, Bp3, BpT1, BpT2, Bpd3, Bpvq, cnorm, loss);
  conv1_k<<<dim3(8, 16, 32), 256, 0, stream>>>(x, W1, eb1, h1);
  conv2_k<<<dim3(4, 8, 32), 256, 0, stream>>>(h1, Bp2, eb2, h2);
  conv3e_k<<<dim3(4, 8, 32), 256, 0, stream>>>(h2, Bp3, eb3, z);
  vqm_k<<<256, 256, 0, stream>>>(z, Bpvq, cnorm, cb, q, loss);
  convt1_k<<<dim3(4, 16, 32), 256, 0, stream>>>(q, BpT1, db1, d1);
  tail_k<<<dim3(9, 43, 32), 256, 0, stream>>>(d1, BpT2, db2, Bpd3, db3, out);
}